// Round 3
// baseline (11070.792 us; speedup 1.0000x reference)
//
#include <hip/hip_runtime.h>
#include <hip/hip_bf16.h>

#define N_NODES 50000
#define N_EDGES 400000
#define N_ETOT  (N_EDGES + N_NODES)
#define NHEADS  4

static constexpr float NEG_SLOPE = 0.2f;
static constexpr float EPS_ = 1e-16f;

__device__ __forceinline__ float b2f(__hip_bfloat16 v) { return __bfloat162float(v); }
// dual-dtype load of external tensors: isbf chosen at runtime by the detector
__device__ __forceinline__ float ldf(const void* p, long i, int isbf) {
    return isbf ? b2f(((const __hip_bfloat16*)p)[i]) : ((const float*)p)[i];
}

// ---------------- dtype detector: bf16 buffers have only sane values at even slots;
// f32 buffers read as bf16 have random exponents (wild/NaN) at even slots ----------------
__global__ __launch_bounds__(256)
void detect_kernel(const void* __restrict__ x, int* __restrict__ flag)
{
    __shared__ int cnt;
    if (threadIdx.x == 0) cnt = 0;
    __syncthreads();
    int local = 0;
    const __hip_bfloat16* p = (const __hip_bfloat16*)x;
    for (int i = threadIdx.x; i < 4096; i += 256) {
        float v = b2f(p[2 * i]);           // even slots = f32 low halves if underlying f32
        if (!(fabsf(v) < 64.f)) local++;   // catches huge + NaN/Inf
    }
    atomicAdd(&cnt, local);
    __syncthreads();
    if (threadIdx.x == 0) *flag = (cnt < 64) ? 1 : 0;   // 1 => buffers are bf16
}

// ---------------- linear: out[N,64] = hin[N,64] @ W[:, col0:col0+64] + b[col0:] ----------------
template<bool EXTIN>
__global__ __launch_bounds__(256)
void lin64_kernel(const void* __restrict__ hin, const void* __restrict__ W,
                  const void* __restrict__ bias, int ldW, int col0,
                  float* __restrict__ out, const int* __restrict__ flagp)
{
    const int isbf = *flagp;
    __shared__ float sW[64 * 64];
    __shared__ float sh[4][64];
    const int t = threadIdx.x;
    for (int i = t; i < 64 * 64; i += 256) {
        int k = i >> 6, c = i & 63;
        sW[i] = ldf(W, (long)k * ldW + col0 + c, isbf);
    }
    const int row0 = blockIdx.x * 4;
    {
        int r = t >> 6, k = t & 63;
        int rr = row0 + r;
        float v = 0.f;
        if (rr < N_NODES)
            v = EXTIN ? ldf(hin, (long)rr * 64 + k, isbf)
                      : ((const float*)hin)[(long)rr * 64 + k];
        sh[r][k] = v;
    }
    __syncthreads();
    const int r = t >> 6, c = t & 63;
    const int rr = row0 + r;
    if (rr >= N_NODES) return;
    float acc = ldf(bias, col0 + c, isbf);
#pragma unroll
    for (int k = 0; k < 64; ++k) acc += sh[r][k] * sW[k * 64 + c];
    out[(long)rr * 64 + c] = acc;
}

// ======== layers 0/1: per-(edge,head) threads, C=16, all 4 heads at once ========
__global__ __launch_bounds__(256)
void edge_score16_kernel(const int* __restrict__ ei, const float* __restrict__ xl,
                         const float* __restrict__ xr, const void* __restrict__ att,
                         float* __restrict__ alpha, unsigned* __restrict__ amax,
                         const int* __restrict__ flagp)
{
    const int isbf = *flagp;
    const int idx = blockIdx.x * blockDim.x + threadIdx.x;
    if (idx >= N_ETOT * NHEADS) return;
    const int e = idx >> 2, h = idx & 3;
    int s, d;
    if (e < N_EDGES) { s = ei[e]; d = ei[N_EDGES + e]; } else { s = d = e - N_EDGES; }
    const float* pl = xl + (long)s * 64 + h * 16;
    const float* pr = xr + (long)d * 64 + h * 16;
    float acc = 0.f;
#pragma unroll
    for (int c = 0; c < 16; ++c) {
        float v = pl[c] + pr[c];
        v = v > 0.f ? v : NEG_SLOPE * v;
        acc += v * ldf(att, h * 16 + c, isbf);
    }
    alpha[idx] = acc;
    unsigned bits = __float_as_uint(acc);
    unsigned key = (bits & 0x80000000u) ? ~bits : (bits | 0x80000000u);
    atomicMax(&amax[d * NHEADS + h], key);
}

__global__ __launch_bounds__(256)
void edge_exp4_kernel(const int* __restrict__ ei, float* __restrict__ alpha,
                      const unsigned* __restrict__ amax, float* __restrict__ denom)
{
    const int idx = blockIdx.x * blockDim.x + threadIdx.x;
    if (idx >= N_ETOT * NHEADS) return;
    const int e = idx >> 2, h = idx & 3;
    const int d = (e < N_EDGES) ? ei[N_EDGES + e] : e - N_EDGES;
    const unsigned key = amax[d * NHEADS + h];
    const unsigned bits = (key & 0x80000000u) ? (key & 0x7FFFFFFFu) : ~key;
    const float m = __uint_as_float(bits);
    const float w = __expf(alpha[idx] - m);
    alpha[idx] = w;
    atomicAdd(&denom[d * NHEADS + h], w);
}

__global__ __launch_bounds__(256)
void edge_scatter16_kernel(const int* __restrict__ ei, const float* __restrict__ xl,
                           const float* __restrict__ alpha, const float* __restrict__ denom,
                           float* __restrict__ accum)
{
    const int idx = blockIdx.x * blockDim.x + threadIdx.x;
    if (idx >= N_ETOT * NHEADS) return;
    const int e = idx >> 2, h = idx & 3;
    int s, d;
    if (e < N_EDGES) { s = ei[e]; d = ei[N_EDGES + e]; } else { s = d = e - N_EDGES; }
    const float w = alpha[idx] / (denom[d * NHEADS + h] + EPS_);
    const float* pl = xl + (long)s * 64 + h * 16;
    float* pa = accum + (long)d * 64 + h * 16;
#pragma unroll
    for (int c = 0; c < 16; ++c) atomicAdd(&pa[c], pl[c] * w);
}

// ======== layer 2: per-edge threads, one head at a time (C=64) ========
__global__ __launch_bounds__(256)
void edge_score64_kernel(const int* __restrict__ ei, const float* __restrict__ xl,
                         const float* __restrict__ xr, const void* __restrict__ att,
                         int att0, float* __restrict__ alpha, unsigned* __restrict__ amax,
                         const int* __restrict__ flagp)
{
    const int isbf = *flagp;
    const int e = blockIdx.x * blockDim.x + threadIdx.x;
    if (e >= N_ETOT) return;
    int s, d;
    if (e < N_EDGES) { s = ei[e]; d = ei[N_EDGES + e]; } else { s = d = e - N_EDGES; }
    const float* pl = xl + (long)s * 64;
    const float* pr = xr + (long)d * 64;
    float acc = 0.f;
#pragma unroll
    for (int c = 0; c < 64; ++c) {
        float v = pl[c] + pr[c];
        v = v > 0.f ? v : NEG_SLOPE * v;
        acc += v * ldf(att, att0 + c, isbf);
    }
    alpha[e] = acc;
    unsigned bits = __float_as_uint(acc);
    unsigned key = (bits & 0x80000000u) ? ~bits : (bits | 0x80000000u);
    atomicMax(&amax[d], key);
}

__global__ __launch_bounds__(256)
void edge_exp1_kernel(const int* __restrict__ ei, float* __restrict__ alpha,
                      const unsigned* __restrict__ amax, float* __restrict__ denom)
{
    const int e = blockIdx.x * blockDim.x + threadIdx.x;
    if (e >= N_ETOT) return;
    const int d = (e < N_EDGES) ? ei[N_EDGES + e] : e - N_EDGES;
    const unsigned key = amax[d];
    const unsigned bits = (key & 0x80000000u) ? (key & 0x7FFFFFFFu) : ~key;
    const float m = __uint_as_float(bits);
    const float w = __expf(alpha[e] - m);
    alpha[e] = w;
    atomicAdd(&denom[d], w);
}

__global__ __launch_bounds__(256)
void edge_scatter64_kernel(const int* __restrict__ ei, const float* __restrict__ xl,
                           const float* __restrict__ alpha, const float* __restrict__ denom,
                           float* __restrict__ accum)
{
    const int e = blockIdx.x * blockDim.x + threadIdx.x;
    if (e >= N_ETOT) return;
    int s, d;
    if (e < N_EDGES) { s = ei[e]; d = ei[N_EDGES + e]; } else { s = d = e - N_EDGES; }
    const float w = alpha[e] / (denom[d] + EPS_);
    const float* pl = xl + (long)s * 64;
    float* pa = accum + (long)d * 64;
#pragma unroll
    for (int c = 0; c < 64; ++c) atomicAdd(&pa[c], pl[c] * w);
}

// ---------------- finalize ----------------
__global__ __launch_bounds__(256)
void finalize_cat_kernel(const float* __restrict__ accum, const void* __restrict__ bias,
                         float* __restrict__ hout, const int* __restrict__ flagp)
{
    const int isbf = *flagp;
    const int idx = blockIdx.x * blockDim.x + threadIdx.x;
    if (idx >= N_NODES * 64) return;
    float v = accum[idx] + ldf(bias, idx & 63, isbf);
    v = v > 0.f ? v : (__expf(v) - 1.f);
    hout[idx] = v;
}

__global__ __launch_bounds__(256)
void finalize_mean_kernel(const float* __restrict__ accum, const void* __restrict__ bias,
                          void* __restrict__ out, const int* __restrict__ flagp)
{
    const int isbf = *flagp;
    const int idx = blockIdx.x * blockDim.x + threadIdx.x;
    if (idx >= N_NODES * 64) return;
    float s = accum[idx] * 0.25f + ldf(bias, idx & 63, isbf);
    if (isbf) ((__hip_bfloat16*)out)[idx] = __float2bfloat16(s);
    else      ((float*)out)[idx] = s;
}

static inline int cdiv(int a, int b) { return (a + b - 1) / b; }

extern "C" void kernel_launch(void* const* d_in, const int* in_sizes, int n_in,
                              void* d_out, int out_size, void* d_ws, size_t ws_size,
                              hipStream_t stream)
{
    const void* x   = d_in[0];
    const int*  ei  = (const int*)d_in[1];
    const void* Wl0 = d_in[2];  const void* bl0 = d_in[3];
    const void* Wr0 = d_in[4];  const void* br0 = d_in[5];
    const void* att0  = d_in[6];  const void* bias0 = d_in[7];
    const void* Wl1 = d_in[8];  const void* bl1 = d_in[9];
    const void* Wr1 = d_in[10]; const void* br1 = d_in[11];
    const void* att1  = d_in[12]; const void* bias1 = d_in[13];
    const void* Wl2 = d_in[14]; const void* bl2 = d_in[15];
    const void* Wr2 = d_in[16]; const void* br2 = d_in[17];
    const void* att2  = d_in[18]; const void* bias2 = d_in[19];

    // workspace layout (f32 elements) — 60.0 MB total
    float*    ws    = (float*)d_ws;
    float*    hbuf  = ws;                          //  3.2M
    float*    xl    = ws +  3200000;               //  3.2M
    float*    xr    = ws +  6400000;               //  3.2M
    float*    accum = ws +  9600000;               //  3.2M
    float*    alpha = ws + 12800000;               //  1.8M
    unsigned* amax  = (unsigned*)(ws + 14600000);  //  0.2M
    float*    denom = ws + 14800000;               //  0.2M
    int*      flag  = (int*)(ws + 15000000);

    const int NG  = cdiv(N_NODES, 4);              // lin/finalize node blocks (x64 threads)
    const int EG4 = cdiv(N_ETOT * NHEADS, 256);    // per-(edge,head)
    const int EG1 = cdiv(N_ETOT, 256);             // per-edge

    detect_kernel<<<1, 256, 0, stream>>>(x, flag);

    // ---- layer 0 ----
    lin64_kernel<true><<<NG, 256, 0, stream>>>(x, Wl0, bl0, 64, 0, xl, flag);
    lin64_kernel<true><<<NG, 256, 0, stream>>>(x, Wr0, br0, 64, 0, xr, flag);
    hipMemsetAsync(amax, 0, 400000 * 4, stream);   // amax + denom (contiguous)
    hipMemsetAsync(accum, 0, (size_t)N_NODES * 64 * 4, stream);
    edge_score16_kernel<<<EG4, 256, 0, stream>>>(ei, xl, xr, att0, alpha, amax, flag);
    edge_exp4_kernel<<<EG4, 256, 0, stream>>>(ei, alpha, amax, denom);
    edge_scatter16_kernel<<<EG4, 256, 0, stream>>>(ei, xl, alpha, denom, accum);
    finalize_cat_kernel<<<NG * 4 / 4, 256, 0, stream>>>(accum, bias0, hbuf, flag);

    // ---- layer 1 ----
    lin64_kernel<false><<<NG, 256, 0, stream>>>(hbuf, Wl1, bl1, 64, 0, xl, flag);
    lin64_kernel<false><<<NG, 256, 0, stream>>>(hbuf, Wr1, br1, 64, 0, xr, flag);
    hipMemsetAsync(amax, 0, 400000 * 4, stream);
    hipMemsetAsync(accum, 0, (size_t)N_NODES * 64 * 4, stream);
    edge_score16_kernel<<<EG4, 256, 0, stream>>>(ei, xl, xr, att1, alpha, amax, flag);
    edge_exp4_kernel<<<EG4, 256, 0, stream>>>(ei, alpha, amax, denom);
    edge_scatter16_kernel<<<EG4, 256, 0, stream>>>(ei, xl, alpha, denom, accum);
    finalize_cat_kernel<<<NG, 256, 0, stream>>>(accum, bias1, hbuf, flag);

    // ---- layer 2: one head at a time, joint accumulation ----
    hipMemsetAsync(accum, 0, (size_t)N_NODES * 64 * 4, stream);
    for (int h = 0; h < NHEADS; ++h) {
        lin64_kernel<false><<<NG, 256, 0, stream>>>(hbuf, Wl2, bl2, 256, h * 64, xl, flag);
        lin64_kernel<false><<<NG, 256, 0, stream>>>(hbuf, Wr2, br2, 256, h * 64, xr, flag);
        hipMemsetAsync(amax, 0, 400000 * 4, stream);
        edge_score64_kernel<<<EG1, 256, 0, stream>>>(ei, xl, xr, att2, h * 64, alpha, amax, flag);
        edge_exp1_kernel<<<EG1, 256, 0, stream>>>(ei, alpha, amax, denom);
        edge_scatter64_kernel<<<EG1, 256, 0, stream>>>(ei, xl, alpha, denom, accum);
    }
    finalize_mean_kernel<<<NG, 256, 0, stream>>>(accum, bias2, d_out, flag);
}

// Round 4
// 820.072 us; speedup vs baseline: 13.4998x; 13.4998x over previous
//
#include <hip/hip_runtime.h>
#include <hip/hip_bf16.h>

#define N_NODES 50000
#define N_EDGES 400000
#define N_ETOT  (N_EDGES + N_NODES)
#define NHEADS  4

static constexpr float NEG_SLOPE = 0.2f;
static constexpr float EPS_ = 1e-16f;

__device__ __forceinline__ float b2f(__hip_bfloat16 v) { return __bfloat162float(v); }
// dual-dtype load of external tensors: isbf chosen at runtime by the detector
__device__ __forceinline__ float ldf(const void* p, long i, int isbf) {
    return isbf ? b2f(((const __hip_bfloat16*)p)[i]) : ((const float*)p)[i];
}

// ---------------- dtype detector (unchanged, proven) ----------------
__global__ __launch_bounds__(256)
void detect_kernel(const void* __restrict__ x, int* __restrict__ flag)
{
    __shared__ int cnt;
    if (threadIdx.x == 0) cnt = 0;
    __syncthreads();
    int local = 0;
    const __hip_bfloat16* p = (const __hip_bfloat16*)x;
    for (int i = threadIdx.x; i < 4096; i += 256) {
        float v = b2f(p[2 * i]);
        if (!(fabsf(v) < 64.f)) local++;
    }
    atomicAdd(&cnt, local);
    __syncthreads();
    if (threadIdx.x == 0) *flag = (cnt < 64) ? 1 : 0;
}

// ---------------- CSR build: count / scan / fill ----------------
__global__ __launch_bounds__(256)
void count_kernel(const int* __restrict__ ei, int* __restrict__ counts)
{
    const int e = blockIdx.x * 256 + threadIdx.x;
    if (e >= N_ETOT) return;
    const int d = (e < N_EDGES) ? ei[N_EDGES + e] : e - N_EDGES;
    atomicAdd(&counts[d], 1);
}

__global__ __launch_bounds__(256)
void scan_kernel(const int* __restrict__ counts, int* __restrict__ offsets)
{
    __shared__ int part[256];
    const int t = threadIdx.x;
    const int CH = (N_NODES + 255) / 256;   // 196
    const int base = t * CH;
    int sum = 0;
    for (int i = 0; i < CH; ++i) {
        int idx = base + i;
        if (idx < N_NODES) sum += counts[idx];
    }
    part[t] = sum;
    __syncthreads();
    for (int off = 1; off < 256; off <<= 1) {
        int u = (t >= off) ? part[t - off] : 0;
        __syncthreads();
        part[t] += u;
        __syncthreads();
    }
    int run = part[t] - sum;                // exclusive prefix of this chunk
    for (int i = 0; i < CH; ++i) {
        int idx = base + i;
        if (idx < N_NODES) { offsets[idx] = run; run += counts[idx]; }
    }
    if (t == 255) offsets[N_NODES] = part[255];
}

__global__ __launch_bounds__(256)
void fill_kernel(const int* __restrict__ ei, const int* __restrict__ offsets,
                 int* __restrict__ cursor, int* __restrict__ csr_src)
{
    const int e = blockIdx.x * 256 + threadIdx.x;
    if (e >= N_ETOT) return;
    int s, d;
    if (e < N_EDGES) { s = ei[e]; d = ei[N_EDGES + e]; } else { s = d = e - N_EDGES; }
    const int pos = atomicAdd(&cursor[d], 1);
    csr_src[offsets[d] + pos] = s;
}

// ---------------- linear: out[N,64] = hin[N,64] @ W[:, col0:col0+64] + b ----------------
template<bool EXTIN>
__global__ __launch_bounds__(256)
void lin_kernel(const void* __restrict__ hin, const void* __restrict__ W,
                const void* __restrict__ bias, int ldW, int col0,
                float* __restrict__ out, const int* __restrict__ flagp)
{
    const int isbf = *flagp;
    __shared__ float sW[64 * 64];
    __shared__ float sh[32][64];
    const int t = threadIdx.x;
    for (int i = t; i < 4096; i += 256) {
        int k = i >> 6, c = i & 63;
        sW[i] = ldf(W, (long)k * ldW + col0 + c, isbf);
    }
    const int row0 = blockIdx.x * 32;
    for (int i = t; i < 32 * 64; i += 256) {
        int r = i >> 6, k = i & 63;
        int rr = row0 + r;
        sh[r][k] = (rr < N_NODES)
            ? (EXTIN ? ldf(hin, (long)rr * 64 + k, isbf) : ((const float*)hin)[(long)rr * 64 + k])
            : 0.f;
    }
    __syncthreads();
    const int c = t & 63;
    const int r0 = (t >> 6) * 8;
    float acc[8];
    const float b = ldf(bias, col0 + c, isbf);
#pragma unroll
    for (int j = 0; j < 8; ++j) acc[j] = b;
    for (int k = 0; k < 64; ++k) {
        const float w = sW[k * 64 + c];
#pragma unroll
        for (int j = 0; j < 8; ++j) acc[j] += sh[r0 + j][k] * w;
    }
#pragma unroll
    for (int j = 0; j < 8; ++j) {
        const int rr = row0 + r0 + j;
        if (rr < N_NODES) out[(long)rr * 64 + c] = acc[j];
    }
}

// ---------------- fused attention, layers 0/1: wave per node, 4 heads x C=16 ----------------
// lane = h*16 + c; online softmax per 16-lane head group; writes bias+ELU'd output.
__global__ __launch_bounds__(256)
void gat_fused16_kernel(const int* __restrict__ csr_src, const int* __restrict__ offsets,
                        const float* __restrict__ xl, const float* __restrict__ xr,
                        const void* __restrict__ att, const void* __restrict__ bias,
                        float* __restrict__ hout, const int* __restrict__ flagp)
{
    const int isbf = *flagp;
    const int node = blockIdx.x * 4 + (threadIdx.x >> 6);
    if (node >= N_NODES) return;
    const int lane = threadIdx.x & 63;
    const float attv = ldf(att, lane, isbf);
    const float xrv = xr[(long)node * 64 + lane];
    const int beg = offsets[node], end = offsets[node + 1];
    float m = -INFINITY, s = 0.f, acc = 0.f;
    for (int p = beg; p < end; ++p) {
        const int src = csr_src[p];
        const float xlv = xl[(long)src * 64 + lane];
        float v = xlv + xrv;
        v = v > 0.f ? v : NEG_SLOPE * v;
        float t = v * attv;
        t += __shfl_xor(t, 1); t += __shfl_xor(t, 2);
        t += __shfl_xor(t, 4); t += __shfl_xor(t, 8);
        const float mn = fmaxf(m, t);
        const float scale = __expf(m - mn);   // 0 on first iter (m=-inf)
        const float w = __expf(t - mn);
        s = s * scale + w;
        acc = acc * scale + w * xlv;
        m = mn;
    }
    float o = acc / (s + EPS_) + ldf(bias, lane, isbf);
    o = o > 0.f ? o : (__expf(o) - 1.f);      // ELU
    hout[(long)node * 64 + lane] = o;
}

// ---------------- fused attention, layer 2: wave per node, one head (C=64) ----------------
__global__ __launch_bounds__(256)
void gat_fused64_kernel(const int* __restrict__ csr_src, const int* __restrict__ offsets,
                        const float* __restrict__ xl, const float* __restrict__ xr,
                        const void* __restrict__ att, int att0,
                        float* __restrict__ accum, int first, const int* __restrict__ flagp)
{
    const int isbf = *flagp;
    const int node = blockIdx.x * 4 + (threadIdx.x >> 6);
    if (node >= N_NODES) return;
    const int lane = threadIdx.x & 63;
    const float attv = ldf(att, att0 + lane, isbf);
    const float xrv = xr[(long)node * 64 + lane];
    const int beg = offsets[node], end = offsets[node + 1];
    float m = -INFINITY, s = 0.f, acc = 0.f;
    for (int p = beg; p < end; ++p) {
        const int src = csr_src[p];
        const float xlv = xl[(long)src * 64 + lane];
        float v = xlv + xrv;
        v = v > 0.f ? v : NEG_SLOPE * v;
        float t = v * attv;
        t += __shfl_xor(t, 1);  t += __shfl_xor(t, 2);  t += __shfl_xor(t, 4);
        t += __shfl_xor(t, 8);  t += __shfl_xor(t, 16); t += __shfl_xor(t, 32);
        const float mn = fmaxf(m, t);
        const float scale = __expf(m - mn);
        const float w = __expf(t - mn);
        s = s * scale + w;
        acc = acc * scale + w * xlv;
        m = mn;
    }
    const float o = acc / (s + EPS_);
    float* pa = accum + (long)node * 64 + lane;
    if (first) *pa = o; else *pa += o;
}

// ---------------- finalize: mean over heads + bias -> out (dual dtype) ----------------
__global__ __launch_bounds__(256)
void finalize_mean_kernel(const float* __restrict__ accum, const void* __restrict__ bias,
                          void* __restrict__ out, const int* __restrict__ flagp)
{
    const int isbf = *flagp;
    const int idx = blockIdx.x * blockDim.x + threadIdx.x;
    if (idx >= N_NODES * 64) return;
    const float s = accum[idx] * 0.25f + ldf(bias, idx & 63, isbf);
    if (isbf) ((__hip_bfloat16*)out)[idx] = __float2bfloat16(s);
    else      ((float*)out)[idx] = s;
}

static inline int cdiv(int a, int b) { return (a + b - 1) / b; }

extern "C" void kernel_launch(void* const* d_in, const int* in_sizes, int n_in,
                              void* d_out, int out_size, void* d_ws, size_t ws_size,
                              hipStream_t stream)
{
    const void* x   = d_in[0];
    const int*  ei  = (const int*)d_in[1];
    const void* Wl0 = d_in[2];  const void* bl0 = d_in[3];
    const void* Wr0 = d_in[4];  const void* br0 = d_in[5];
    const void* att0  = d_in[6];  const void* bias0 = d_in[7];
    const void* Wl1 = d_in[8];  const void* bl1 = d_in[9];
    const void* Wr1 = d_in[10]; const void* br1 = d_in[11];
    const void* att1  = d_in[12]; const void* bias1 = d_in[13];
    const void* Wl2 = d_in[14]; const void* bl2 = d_in[15];
    const void* Wr2 = d_in[16]; const void* br2 = d_in[17];
    const void* att2  = d_in[18]; const void* bias2 = d_in[19];

    // workspace layout (f32/int32 elements), ~54 MB
    float* ws     = (float*)d_ws;
    float* hbuf   = ws;                         // 3.2M f32
    float* xl     = ws +  3200000;              // 3.2M
    float* xr     = ws +  6400000;              // 3.2M
    float* accum  = ws +  9600000;              // 3.2M
    int*   csr    = (int*)(ws + 12800000);      // 450k
    int*   offs   = csr + 450000;               // 50001
    int*   counts = offs + 50008;               // 50k (reused as cursor)
    int*   flag   = counts + 50000;

    const int NGE = cdiv(N_ETOT, 256);          // edge-parallel blocks
    const int NGW = cdiv(N_NODES, 4);           // wave-per-node blocks
    const int NGL = cdiv(N_NODES, 32);          // linear blocks
    const int NGF = cdiv(N_NODES * 64, 256);

    detect_kernel<<<1, 256, 0, stream>>>(x, flag);

    // ---- CSR build (dst-sorted adjacency) ----
    hipMemsetAsync(counts, 0, 50000 * 4, stream);
    count_kernel<<<NGE, 256, 0, stream>>>(ei, counts);
    scan_kernel<<<1, 256, 0, stream>>>(counts, offs);
    hipMemsetAsync(counts, 0, 50000 * 4, stream);       // reuse as cursor
    fill_kernel<<<NGE, 256, 0, stream>>>(ei, offs, counts, csr);

    // ---- layer 0 ----
    lin_kernel<true><<<NGL, 256, 0, stream>>>(x, Wl0, bl0, 64, 0, xl, flag);
    lin_kernel<true><<<NGL, 256, 0, stream>>>(x, Wr0, br0, 64, 0, xr, flag);
    gat_fused16_kernel<<<NGW, 256, 0, stream>>>(csr, offs, xl, xr, att0, bias0, hbuf, flag);

    // ---- layer 1 ----
    lin_kernel<false><<<NGL, 256, 0, stream>>>(hbuf, Wl1, bl1, 64, 0, xl, flag);
    lin_kernel<false><<<NGL, 256, 0, stream>>>(hbuf, Wr1, br1, 64, 0, xr, flag);
    gat_fused16_kernel<<<NGW, 256, 0, stream>>>(csr, offs, xl, xr, att1, bias1, hbuf, flag);

    // ---- layer 2: head-at-a-time, joint accumulation ----
    for (int h = 0; h < NHEADS; ++h) {
        lin_kernel<false><<<NGL, 256, 0, stream>>>(hbuf, Wl2, bl2, 256, h * 64, xl, flag);
        lin_kernel<false><<<NGL, 256, 0, stream>>>(hbuf, Wr2, br2, 256, h * 64, xr, flag);
        gat_fused64_kernel<<<NGW, 256, 0, stream>>>(csr, offs, xl, xr, att2, h * 64,
                                                    accum, h == 0, flag);
    }
    finalize_mean_kernel<<<NGF, 256, 0, stream>>>(accum, bias2, d_out, flag);
}

// Round 5
// 580.623 us; speedup vs baseline: 19.0671x; 1.4124x over previous
//
#include <hip/hip_runtime.h>
#include <hip/hip_bf16.h>

#define N_NODES 50000
#define N_EDGES 400000
#define N_ETOT  (N_EDGES + N_NODES)
#define NHEADS  4
#define SCAN_BLOCKS 196   // cdiv(N_NODES, 256)

static constexpr float NEG_SLOPE = 0.2f;
static constexpr float EPS_ = 1e-16f;

__device__ __forceinline__ float b2f(__hip_bfloat16 v) { return __bfloat162float(v); }
// dual-dtype load of external tensors: isbf chosen at runtime by the detector
__device__ __forceinline__ float ldf(const void* p, long i, int isbf) {
    return isbf ? b2f(((const __hip_bfloat16*)p)[i]) : ((const float*)p)[i];
}

// ---------------- dtype detector (proven) ----------------
__global__ __launch_bounds__(256)
void detect_kernel(const void* __restrict__ x, int* __restrict__ flag)
{
    __shared__ int cnt;
    if (threadIdx.x == 0) cnt = 0;
    __syncthreads();
    int local = 0;
    const __hip_bfloat16* p = (const __hip_bfloat16*)x;
    for (int i = threadIdx.x; i < 4096; i += 256) {
        float v = b2f(p[2 * i]);
        if (!(fabsf(v) < 64.f)) local++;
    }
    atomicAdd(&cnt, local);
    __syncthreads();
    if (threadIdx.x == 0) *flag = (cnt < 64) ? 1 : 0;
}

// ---------------- CSR build ----------------
__global__ __launch_bounds__(256)
void count_kernel(const int* __restrict__ ei, int* __restrict__ counts)
{
    const int e = blockIdx.x * 256 + threadIdx.x;
    if (e >= N_ETOT) return;
    const int d = (e < N_EDGES) ? ei[N_EDGES + e] : e - N_EDGES;
    atomicAdd(&counts[d], 1);
}

// 3-phase hierarchical exclusive scan of counts[50000] -> offs[50001]
__global__ __launch_bounds__(256)
void scan_phase1(const int* __restrict__ counts, int* __restrict__ bsum)
{
    __shared__ int sh[256];
    const int idx = blockIdx.x * 256 + threadIdx.x;
    sh[threadIdx.x] = (idx < N_NODES) ? counts[idx] : 0;
    __syncthreads();
    for (int off = 128; off > 0; off >>= 1) {
        if (threadIdx.x < off) sh[threadIdx.x] += sh[threadIdx.x + off];
        __syncthreads();
    }
    if (threadIdx.x == 0) bsum[blockIdx.x] = sh[0];
}

__global__ __launch_bounds__(256)
void scan_phase2(const int* __restrict__ bsum, int* __restrict__ bpre, int* __restrict__ offs)
{
    __shared__ int sh[256];
    const int t = threadIdx.x;
    const int v = (t < SCAN_BLOCKS) ? bsum[t] : 0;
    sh[t] = v;
    __syncthreads();
    for (int off = 1; off < 256; off <<= 1) {
        int u = (t >= off) ? sh[t - off] : 0;
        __syncthreads();
        sh[t] += u;
        __syncthreads();
    }
    if (t < SCAN_BLOCKS) bpre[t] = sh[t] - v;   // exclusive
    if (t == 0) offs[N_NODES] = N_ETOT;
}

__global__ __launch_bounds__(256)
void scan_phase3(const int* __restrict__ counts, const int* __restrict__ bpre,
                 int* __restrict__ offs)
{
    __shared__ int sh[256];
    const int t = threadIdx.x;
    const int idx = blockIdx.x * 256 + t;
    const int v = (idx < N_NODES) ? counts[idx] : 0;
    sh[t] = v;
    __syncthreads();
    for (int off = 1; off < 256; off <<= 1) {
        int u = (t >= off) ? sh[t - off] : 0;
        __syncthreads();
        sh[t] += u;
        __syncthreads();
    }
    if (idx < N_NODES) offs[idx] = bpre[blockIdx.x] + sh[t] - v;
}

__global__ __launch_bounds__(256)
void fill_kernel(const int* __restrict__ ei, const int* __restrict__ offsets,
                 int* __restrict__ cursor, int* __restrict__ csr_src)
{
    const int e = blockIdx.x * 256 + threadIdx.x;
    if (e >= N_ETOT) return;
    int s, d;
    if (e < N_EDGES) { s = ei[e]; d = ei[N_EDGES + e]; } else { s = d = e - N_EDGES; }
    const int pos = atomicAdd(&cursor[d], 1);
    csr_src[offsets[d] + pos] = s;
}

// ---------------- linear: out[N,64](bf16) = hin[N,64] @ W[:, col0:col0+64] + b ----------------
template<bool EXTIN>
__global__ __launch_bounds__(256)
void lin_kernel(const void* __restrict__ hin, const void* __restrict__ W,
                const void* __restrict__ bias, int ldW, int col0,
                __hip_bfloat16* __restrict__ out, const int* __restrict__ flagp)
{
    const int isbf = *flagp;
    __shared__ float sW[64 * 64];
    __shared__ float sh[32][64];
    const int t = threadIdx.x;
    for (int i = t; i < 4096; i += 256) {
        int k = i >> 6, c = i & 63;
        sW[i] = ldf(W, (long)k * ldW + col0 + c, isbf);
    }
    const int row0 = blockIdx.x * 32;
    for (int i = t; i < 32 * 64; i += 256) {
        int r = i >> 6, k = i & 63;
        int rr = row0 + r;
        sh[r][k] = (rr < N_NODES)
            ? (EXTIN ? ldf(hin, (long)rr * 64 + k, isbf) : ((const float*)hin)[(long)rr * 64 + k])
            : 0.f;
    }
    __syncthreads();
    const int c = t & 63;
    const int r0 = (t >> 6) * 8;
    float acc[8];
    const float b = ldf(bias, col0 + c, isbf);
#pragma unroll
    for (int j = 0; j < 8; ++j) acc[j] = b;
    for (int k = 0; k < 64; ++k) {
        const float w = sW[k * 64 + c];
#pragma unroll
        for (int j = 0; j < 8; ++j) acc[j] += sh[r0 + j][k] * w;
    }
#pragma unroll
    for (int j = 0; j < 8; ++j) {
        const int rr = row0 + r0 + j;
        if (rr < N_NODES) out[(long)rr * 64 + c] = __float2bfloat16(acc[j]);
    }
}

// ---------------- fused attention, layers 0/1: wave/node, 2 edges/iter, bf16 panels ----------
// half-wave per edge; lane covers channels (2*l32, 2*l32+1); head = l32>>3 (16ch per head).
__global__ __launch_bounds__(256)
void gat_fused16_kernel(const int* __restrict__ csr_src, const int* __restrict__ offsets,
                        const __hip_bfloat16* __restrict__ xl, const __hip_bfloat16* __restrict__ xr,
                        const void* __restrict__ att, const void* __restrict__ bias,
                        float* __restrict__ hout, const int* __restrict__ flagp)
{
    const int isbf = *flagp;
    const int node = blockIdx.x * 4 + (threadIdx.x >> 6);
    if (node >= N_NODES) return;
    const int lane = threadIdx.x & 63;
    const int l32 = lane & 31;
    const int half = lane >> 5;
    const int c0 = l32 * 2;
    const float a0 = ldf(att, c0, isbf), a1 = ldf(att, c0 + 1, isbf);
    const __hip_bfloat162 xr2 = ((const __hip_bfloat162*)(xr + (long)node * 64))[l32];
    const float xr0 = b2f(xr2.x), xr1 = b2f(xr2.y);
    const int beg = offsets[node], end = offsets[node + 1];
    float m = -INFINITY, s = 0.f, acc0 = 0.f, acc1 = 0.f;
    for (int p = beg + half; p < end; p += 2) {
        const int src = csr_src[p];
        const __hip_bfloat162 v2 = ((const __hip_bfloat162*)(xl + (long)src * 64))[l32];
        const float xl0 = b2f(v2.x), xl1 = b2f(v2.y);
        float v0 = xl0 + xr0, v1 = xl1 + xr1;
        v0 = v0 > 0.f ? v0 : NEG_SLOPE * v0;
        v1 = v1 > 0.f ? v1 : NEG_SLOPE * v1;
        float t = v0 * a0 + v1 * a1;
        t += __shfl_xor(t, 1); t += __shfl_xor(t, 2); t += __shfl_xor(t, 4);
        const float mn = fmaxf(m, t);
        const float sc = __expf(m - mn);       // 0 on first iter
        const float w  = __expf(t - mn);
        s = s * sc + w;
        acc0 = acc0 * sc + w * xl0;
        acc1 = acc1 * sc + w * xl1;
        m = mn;
    }
    // merge the two half-wave online-softmax states (lane L <-> L^32, same channels)
    {
        const float m_p = __shfl_xor(m, 32);
        const float s_p = __shfl_xor(s, 32);
        const float p0  = __shfl_xor(acc0, 32);
        const float p1  = __shfl_xor(acc1, 32);
        const float mm = fmaxf(m, m_p);
        const float e0 = __expf(m - mm), e1 = __expf(m_p - mm);
        s = s * e0 + s_p * e1;
        acc0 = acc0 * e0 + p0 * e1;
        acc1 = acc1 * e0 + p1 * e1;
    }
    float o0 = acc0 / (s + EPS_) + ldf(bias, c0, isbf);
    float o1 = acc1 / (s + EPS_) + ldf(bias, c0 + 1, isbf);
    o0 = o0 > 0.f ? o0 : (__expf(o0) - 1.f);
    o1 = o1 > 0.f ? o1 : (__expf(o1) - 1.f);
    if (half == 0)
        ((float2*)(hout + (long)node * 64))[l32] = make_float2(o0, o1);
}

// ---------------- fused attention, layer 2: wave/node, 2 edges/iter, one head (C=64) --------
__global__ __launch_bounds__(256)
void gat_fused64_kernel(const int* __restrict__ csr_src, const int* __restrict__ offsets,
                        const __hip_bfloat16* __restrict__ xl, const __hip_bfloat16* __restrict__ xr,
                        const void* __restrict__ att, int att0,
                        float* __restrict__ accum, int first, const int* __restrict__ flagp)
{
    const int isbf = *flagp;
    const int node = blockIdx.x * 4 + (threadIdx.x >> 6);
    if (node >= N_NODES) return;
    const int lane = threadIdx.x & 63;
    const int l32 = lane & 31;
    const int half = lane >> 5;
    const int c0 = l32 * 2;
    const float a0 = ldf(att, att0 + c0, isbf), a1 = ldf(att, att0 + c0 + 1, isbf);
    const __hip_bfloat162 xr2 = ((const __hip_bfloat162*)(xr + (long)node * 64))[l32];
    const float xr0 = b2f(xr2.x), xr1 = b2f(xr2.y);
    const int beg = offsets[node], end = offsets[node + 1];
    float m = -INFINITY, s = 0.f, acc0 = 0.f, acc1 = 0.f;
    for (int p = beg + half; p < end; p += 2) {
        const int src = csr_src[p];
        const __hip_bfloat162 v2 = ((const __hip_bfloat162*)(xl + (long)src * 64))[l32];
        const float xl0 = b2f(v2.x), xl1 = b2f(v2.y);
        float v0 = xl0 + xr0, v1 = xl1 + xr1;
        v0 = v0 > 0.f ? v0 : NEG_SLOPE * v0;
        v1 = v1 > 0.f ? v1 : NEG_SLOPE * v1;
        float t = v0 * a0 + v1 * a1;
        t += __shfl_xor(t, 1); t += __shfl_xor(t, 2); t += __shfl_xor(t, 4);
        t += __shfl_xor(t, 8); t += __shfl_xor(t, 16);
        const float mn = fmaxf(m, t);
        const float sc = __expf(m - mn);
        const float w  = __expf(t - mn);
        s = s * sc + w;
        acc0 = acc0 * sc + w * xl0;
        acc1 = acc1 * sc + w * xl1;
        m = mn;
    }
    {
        const float m_p = __shfl_xor(m, 32);
        const float s_p = __shfl_xor(s, 32);
        const float p0  = __shfl_xor(acc0, 32);
        const float p1  = __shfl_xor(acc1, 32);
        const float mm = fmaxf(m, m_p);
        const float e0 = __expf(m - mm), e1 = __expf(m_p - mm);
        s = s * e0 + s_p * e1;
        acc0 = acc0 * e0 + p0 * e1;
        acc1 = acc1 * e0 + p1 * e1;
    }
    if (half == 0) {
        float2* pa = (float2*)(accum + (long)node * 64) + l32;
        const float o0 = acc0 / (s + EPS_), o1 = acc1 / (s + EPS_);
        if (first) *pa = make_float2(o0, o1);
        else { float2 v = *pa; *pa = make_float2(v.x + o0, v.y + o1); }
    }
}

// ---------------- finalize: mean over heads + bias -> out (dual dtype) ----------------
__global__ __launch_bounds__(256)
void finalize_mean_kernel(const float* __restrict__ accum, const void* __restrict__ bias,
                          void* __restrict__ out, const int* __restrict__ flagp)
{
    const int isbf = *flagp;
    const int idx = blockIdx.x * blockDim.x + threadIdx.x;
    if (idx >= N_NODES * 64) return;
    const float s = accum[idx] * 0.25f + ldf(bias, idx & 63, isbf);
    if (isbf) ((__hip_bfloat16*)out)[idx] = __float2bfloat16(s);
    else      ((float*)out)[idx] = s;
}

static inline int cdiv(int a, int b) { return (a + b - 1) / b; }

extern "C" void kernel_launch(void* const* d_in, const int* in_sizes, int n_in,
                              void* d_out, int out_size, void* d_ws, size_t ws_size,
                              hipStream_t stream)
{
    const void* x   = d_in[0];
    const int*  ei  = (const int*)d_in[1];
    const void* Wl0 = d_in[2];  const void* bl0 = d_in[3];
    const void* Wr0 = d_in[4];  const void* br0 = d_in[5];
    const void* att0  = d_in[6];  const void* bias0 = d_in[7];
    const void* Wl1 = d_in[8];  const void* bl1 = d_in[9];
    const void* Wr1 = d_in[10]; const void* br1 = d_in[11];
    const void* att1  = d_in[12]; const void* bias1 = d_in[13];
    const void* Wl2 = d_in[14]; const void* bl2 = d_in[15];
    const void* Wr2 = d_in[16]; const void* br2 = d_in[17];
    const void* att2  = d_in[18]; const void* bias2 = d_in[19];

    // workspace layout (~41 MB)
    float* ws    = (float*)d_ws;
    float* hbuf  = ws;                                    // 3.2M f32
    float* accum = ws + 3200000;                          // 3.2M f32
    __hip_bfloat16* xl = (__hip_bfloat16*)(ws + 6400000); // 3.2M bf16
    __hip_bfloat16* xr = (__hip_bfloat16*)(ws + 8000000); // 3.2M bf16
    int* csr    = (int*)(ws + 9600000);                   // 450k
    int* offs   = csr + 450000;                           // 50001
    int* counts = offs + 50004;                           // 50k (reused as cursor)
    int* bsum   = counts + 50000;                         // 256
    int* bpre   = bsum + 256;                             // 256
    int* flag   = bpre + 256;

    const int NGE = cdiv(N_ETOT, 256);
    const int NGW = cdiv(N_NODES, 4);
    const int NGL = cdiv(N_NODES, 32);
    const int NGF = cdiv(N_NODES * 64, 256);

    detect_kernel<<<1, 256, 0, stream>>>(x, flag);

    // ---- CSR build ----
    hipMemsetAsync(counts, 0, 50000 * 4, stream);
    count_kernel<<<NGE, 256, 0, stream>>>(ei, counts);
    scan_phase1<<<SCAN_BLOCKS, 256, 0, stream>>>(counts, bsum);
    scan_phase2<<<1, 256, 0, stream>>>(bsum, bpre, offs);
    scan_phase3<<<SCAN_BLOCKS, 256, 0, stream>>>(counts, bpre, offs);
    hipMemsetAsync(counts, 0, 50000 * 4, stream);         // reuse as cursor
    fill_kernel<<<NGE, 256, 0, stream>>>(ei, offs, counts, csr);

    // ---- layer 0 ----
    lin_kernel<true><<<NGL, 256, 0, stream>>>(x, Wl0, bl0, 64, 0, xl, flag);
    lin_kernel<true><<<NGL, 256, 0, stream>>>(x, Wr0, br0, 64, 0, xr, flag);
    gat_fused16_kernel<<<NGW, 256, 0, stream>>>(csr, offs, xl, xr, att0, bias0, hbuf, flag);

    // ---- layer 1 ----
    lin_kernel<false><<<NGL, 256, 0, stream>>>(hbuf, Wl1, bl1, 64, 0, xl, flag);
    lin_kernel<false><<<NGL, 256, 0, stream>>>(hbuf, Wr1, br1, 64, 0, xr, flag);
    gat_fused16_kernel<<<NGW, 256, 0, stream>>>(csr, offs, xl, xr, att1, bias1, hbuf, flag);

    // ---- layer 2: head-at-a-time, joint accumulation ----
    for (int h = 0; h < NHEADS; ++h) {
        lin_kernel<false><<<NGL, 256, 0, stream>>>(hbuf, Wl2, bl2, 256, h * 64, xl, flag);
        lin_kernel<false><<<NGL, 256, 0, stream>>>(hbuf, Wr2, br2, 256, h * 64, xr, flag);
        gat_fused64_kernel<<<NGW, 256, 0, stream>>>(csr, offs, xl, xr, att2, h * 64,
                                                    accum, h == 0, flag);
    }
    finalize_mean_kernel<<<NGF, 256, 0, stream>>>(accum, bias2, d_out, flag);
}

// Round 6
// 497.194 us; speedup vs baseline: 22.2665x; 1.1678x over previous
//
#include <hip/hip_runtime.h>
#include <hip/hip_bf16.h>

#define N_NODES 50000
#define N_EDGES 400000
#define N_ETOT  (N_EDGES + N_NODES)
#define NHEADS  4
#define SCAN_BLOCKS 196   // cdiv(N_NODES, 256)

static constexpr float NEG_SLOPE = 0.2f;
static constexpr float EPS_ = 1e-16f;

__device__ __forceinline__ float b2f(__hip_bfloat16 v) { return __bfloat162float(v); }
__device__ __forceinline__ float ldf(const void* p, long i, int isbf) {
    return isbf ? b2f(((const __hip_bfloat16*)p)[i]) : ((const float*)p)[i];
}

// ---------------- dtype detector (proven) ----------------
__global__ __launch_bounds__(256)
void detect_kernel(const void* __restrict__ x, int* __restrict__ flag)
{
    __shared__ int cnt;
    if (threadIdx.x == 0) cnt = 0;
    __syncthreads();
    int local = 0;
    const __hip_bfloat16* p = (const __hip_bfloat16*)x;
    for (int i = threadIdx.x; i < 4096; i += 256) {
        float v = b2f(p[2 * i]);
        if (!(fabsf(v) < 64.f)) local++;
    }
    atomicAdd(&cnt, local);
    __syncthreads();
    if (threadIdx.x == 0) *flag = (cnt < 64) ? 1 : 0;
}

// ---------------- CSR build ----------------
__global__ __launch_bounds__(256)
void count_kernel(const int* __restrict__ ei, int* __restrict__ counts)
{
    const int e = blockIdx.x * 256 + threadIdx.x;
    if (e >= N_ETOT) return;
    const int d = (e < N_EDGES) ? ei[N_EDGES + e] : e - N_EDGES;
    atomicAdd(&counts[d], 1);
}

__global__ __launch_bounds__(256)
void scan_phase1(const int* __restrict__ counts, int* __restrict__ bsum)
{
    __shared__ int sh[256];
    const int idx = blockIdx.x * 256 + threadIdx.x;
    sh[threadIdx.x] = (idx < N_NODES) ? counts[idx] : 0;
    __syncthreads();
    for (int off = 128; off > 0; off >>= 1) {
        if (threadIdx.x < off) sh[threadIdx.x] += sh[threadIdx.x + off];
        __syncthreads();
    }
    if (threadIdx.x == 0) bsum[blockIdx.x] = sh[0];
}

__global__ __launch_bounds__(256)
void scan_phase2(const int* __restrict__ bsum, int* __restrict__ bpre, int* __restrict__ offs)
{
    __shared__ int sh[256];
    const int t = threadIdx.x;
    const int v = (t < SCAN_BLOCKS) ? bsum[t] : 0;
    sh[t] = v;
    __syncthreads();
    for (int off = 1; off < 256; off <<= 1) {
        int u = (t >= off) ? sh[t - off] : 0;
        __syncthreads();
        sh[t] += u;
        __syncthreads();
    }
    if (t < SCAN_BLOCKS) bpre[t] = sh[t] - v;
    if (t == 0) offs[N_NODES] = N_ETOT;
}

__global__ __launch_bounds__(256)
void scan_phase3(const int* __restrict__ counts, const int* __restrict__ bpre,
                 int* __restrict__ offs)
{
    __shared__ int sh[256];
    const int t = threadIdx.x;
    const int idx = blockIdx.x * 256 + t;
    const int v = (idx < N_NODES) ? counts[idx] : 0;
    sh[t] = v;
    __syncthreads();
    for (int off = 1; off < 256; off <<= 1) {
        int u = (t >= off) ? sh[t - off] : 0;
        __syncthreads();
        sh[t] += u;
        __syncthreads();
    }
    if (idx < N_NODES) offs[idx] = bpre[blockIdx.x] + sh[t] - v;
}

__global__ __launch_bounds__(256)
void fill_kernel(const int* __restrict__ ei, const int* __restrict__ offsets,
                 int* __restrict__ cursor, int* __restrict__ csr_src)
{
    const int e = blockIdx.x * 256 + threadIdx.x;
    if (e >= N_ETOT) return;
    int s, d;
    if (e < N_EDGES) { s = ei[e]; d = ei[N_EDGES + e]; } else { s = d = e - N_EDGES; }
    const int pos = atomicAdd(&cursor[d], 1);
    csr_src[offsets[d] + pos] = s;
}

// ---------------- dual linear: xl/xr[N,DOUT](bf16) = hin[N,64] @ {Wl,Wr} + {bl,br} -------
// EXT: input read via runtime dtype flag; !EXT: input is bf16 (hbuf).
template<int DOUT, bool EXT>
__global__ __launch_bounds__(256)
void lin_dual_kernel(const void* __restrict__ hin,
                     const void* __restrict__ Wl, const void* __restrict__ bl,
                     const void* __restrict__ Wr, const void* __restrict__ br,
                     __hip_bfloat16* __restrict__ xlp, __hip_bfloat16* __restrict__ xrp,
                     const int* __restrict__ flagp)
{
    const int isbf = *flagp;
    __shared__ __hip_bfloat16 sWl[64 * DOUT];
    __shared__ __hip_bfloat16 sWr[64 * DOUT];
    __shared__ float sh[32][64];
    const int t = threadIdx.x;
    for (int i = t; i < 64 * DOUT; i += 256) {
        sWl[i] = __float2bfloat16(ldf(Wl, i, isbf));
        sWr[i] = __float2bfloat16(ldf(Wr, i, isbf));
    }
    const int row0 = blockIdx.x * 32;
    for (int i = t; i < 32 * 64; i += 256) {
        int r = i >> 6, k = i & 63;
        int rr = row0 + r;
        float v = 0.f;
        if (rr < N_NODES)
            v = EXT ? ldf(hin, (long)rr * 64 + k, isbf)
                    : b2f(((const __hip_bfloat16*)hin)[(long)rr * 64 + k]);
        sh[r][k] = v;
    }
    __syncthreads();

    constexpr int RG = 256 / DOUT;        // row-groups handled concurrently (4 or 1)
    constexpr int ROWTILES = 32 / (RG * 8);
    const int c = t % DOUT;
    const int rg = t / DOUT;
    const float bvl = ldf(bl, c, isbf);
    const float bvr = ldf(br, c, isbf);
#pragma unroll
    for (int rt = 0; rt < ROWTILES; ++rt) {
        const int r0 = rt * RG * 8 + rg * 8;
        float accl[8], accr[8];
#pragma unroll
        for (int j = 0; j < 8; ++j) { accl[j] = bvl; accr[j] = bvr; }
        for (int k = 0; k < 64; ++k) {
            const float wl = b2f(sWl[k * DOUT + c]);
            const float wr = b2f(sWr[k * DOUT + c]);
#pragma unroll
            for (int j = 0; j < 8; ++j) {
                const float hv = sh[r0 + j][k];
                accl[j] += hv * wl;
                accr[j] += hv * wr;
            }
        }
#pragma unroll
        for (int j = 0; j < 8; ++j) {
            const int rr = row0 + r0 + j;
            if (rr < N_NODES) {
                xlp[(long)rr * DOUT + c] = __float2bfloat16(accl[j]);
                xrp[(long)rr * DOUT + c] = __float2bfloat16(accr[j]);
            }
        }
    }
}

// ---------------- fused attention, layers 0/1: wave/node, 2 edges/iter ----------------
__global__ __launch_bounds__(256)
void gat_fused16_kernel(const int* __restrict__ csr_src, const int* __restrict__ offsets,
                        const __hip_bfloat16* __restrict__ xl, const __hip_bfloat16* __restrict__ xr,
                        const void* __restrict__ att, const void* __restrict__ bias,
                        __hip_bfloat16* __restrict__ hout, const int* __restrict__ flagp)
{
    const int isbf = *flagp;
    const int node = blockIdx.x * 4 + (threadIdx.x >> 6);
    if (node >= N_NODES) return;
    const int lane = threadIdx.x & 63;
    const int l32 = lane & 31;
    const int half = lane >> 5;
    const int c0 = l32 * 2;
    const float a0 = ldf(att, c0, isbf), a1 = ldf(att, c0 + 1, isbf);
    const __hip_bfloat162 xr2 = ((const __hip_bfloat162*)(xr + (long)node * 64))[l32];
    const float xr0 = b2f(xr2.x), xr1 = b2f(xr2.y);
    const int beg = offsets[node], end = offsets[node + 1];
    float m = -INFINITY, s = 0.f, acc0 = 0.f, acc1 = 0.f;
    for (int p = beg + half; p < end; p += 2) {
        const int src = csr_src[p];
        const __hip_bfloat162 v2 = ((const __hip_bfloat162*)(xl + (long)src * 64))[l32];
        const float xl0 = b2f(v2.x), xl1 = b2f(v2.y);
        float v0 = xl0 + xr0, v1 = xl1 + xr1;
        v0 = v0 > 0.f ? v0 : NEG_SLOPE * v0;
        v1 = v1 > 0.f ? v1 : NEG_SLOPE * v1;
        float t = v0 * a0 + v1 * a1;
        t += __shfl_xor(t, 1); t += __shfl_xor(t, 2); t += __shfl_xor(t, 4);
        const float mn = fmaxf(m, t);
        const float sc = __expf(m - mn);
        const float w  = __expf(t - mn);
        s = s * sc + w;
        acc0 = acc0 * sc + w * xl0;
        acc1 = acc1 * sc + w * xl1;
        m = mn;
    }
    {
        const float m_p = __shfl_xor(m, 32);
        const float s_p = __shfl_xor(s, 32);
        const float p0  = __shfl_xor(acc0, 32);
        const float p1  = __shfl_xor(acc1, 32);
        const float mm = fmaxf(m, m_p);
        const float e0 = __expf(m - mm), e1 = __expf(m_p - mm);
        s = s * e0 + s_p * e1;
        acc0 = acc0 * e0 + p0 * e1;
        acc1 = acc1 * e0 + p1 * e1;
    }
    float o0 = acc0 / (s + EPS_) + ldf(bias, c0, isbf);
    float o1 = acc1 / (s + EPS_) + ldf(bias, c0 + 1, isbf);
    o0 = o0 > 0.f ? o0 : (__expf(o0) - 1.f);
    o1 = o1 > 0.f ? o1 : (__expf(o1) - 1.f);
    if (half == 0) {
        __hip_bfloat162 ov;
        ov.x = __float2bfloat16(o0); ov.y = __float2bfloat16(o1);
        ((__hip_bfloat162*)(hout + (long)node * 64))[l32] = ov;
    }
}

// ---------------- layer 2: block/node, wave/head, fused head-mean+bias+store ------------
__global__ __launch_bounds__(256)
void gat64x4_kernel(const int* __restrict__ csr_src, const int* __restrict__ offsets,
                    const __hip_bfloat16* __restrict__ xl2, const __hip_bfloat16* __restrict__ xr2,
                    const void* __restrict__ att, const void* __restrict__ bias,
                    void* __restrict__ out, const int* __restrict__ flagp)
{
    const int isbf = *flagp;
    const int node = blockIdx.x;
    const int h = threadIdx.x >> 6;
    const int lane = threadIdx.x & 63;
    const int l32 = lane & 31;
    const int half = lane >> 5;
    const int c0 = l32 * 2;
    __shared__ float sh[NHEADS][64];

    const float a0 = ldf(att, h * 64 + c0, isbf), a1 = ldf(att, h * 64 + c0 + 1, isbf);
    const __hip_bfloat162 xrv = ((const __hip_bfloat162*)(xr2 + (long)node * 256 + h * 64))[l32];
    const float xr0 = b2f(xrv.x), xr1 = b2f(xrv.y);
    const int beg = offsets[node], end = offsets[node + 1];
    float m = -INFINITY, s = 0.f, acc0 = 0.f, acc1 = 0.f;
    for (int p = beg + half; p < end; p += 2) {
        const int src = csr_src[p];
        const __hip_bfloat162 v2 = ((const __hip_bfloat162*)(xl2 + (long)src * 256 + h * 64))[l32];
        const float xl0 = b2f(v2.x), xl1 = b2f(v2.y);
        float v0 = xl0 + xr0, v1 = xl1 + xr1;
        v0 = v0 > 0.f ? v0 : NEG_SLOPE * v0;
        v1 = v1 > 0.f ? v1 : NEG_SLOPE * v1;
        float t = v0 * a0 + v1 * a1;
        t += __shfl_xor(t, 1); t += __shfl_xor(t, 2); t += __shfl_xor(t, 4);
        t += __shfl_xor(t, 8); t += __shfl_xor(t, 16);
        const float mn = fmaxf(m, t);
        const float sc = __expf(m - mn);
        const float w  = __expf(t - mn);
        s = s * sc + w;
        acc0 = acc0 * sc + w * xl0;
        acc1 = acc1 * sc + w * xl1;
        m = mn;
    }
    {
        const float m_p = __shfl_xor(m, 32);
        const float s_p = __shfl_xor(s, 32);
        const float p0  = __shfl_xor(acc0, 32);
        const float p1  = __shfl_xor(acc1, 32);
        const float mm = fmaxf(m, m_p);
        const float e0 = __expf(m - mm), e1 = __expf(m_p - mm);
        s = s * e0 + s_p * e1;
        acc0 = acc0 * e0 + p0 * e1;
        acc1 = acc1 * e0 + p1 * e1;
    }
    if (half == 0) {
        sh[h][c0]     = acc0 / (s + EPS_);
        sh[h][c0 + 1] = acc1 / (s + EPS_);
    }
    __syncthreads();
    if (threadIdx.x < 64) {
        const int d = threadIdx.x;
        const float v = (sh[0][d] + sh[1][d] + sh[2][d] + sh[3][d]) * 0.25f
                        + ldf(bias, d, isbf);
        if (isbf) ((__hip_bfloat16*)out)[(long)node * 64 + d] = __float2bfloat16(v);
        else      ((float*)out)[(long)node * 64 + d] = v;
    }
}

static inline int cdiv(int a, int b) { return (a + b - 1) / b; }

extern "C" void kernel_launch(void* const* d_in, const int* in_sizes, int n_in,
                              void* d_out, int out_size, void* d_ws, size_t ws_size,
                              hipStream_t stream)
{
    const void* x   = d_in[0];
    const int*  ei  = (const int*)d_in[1];
    const void* Wl0 = d_in[2];  const void* bl0 = d_in[3];
    const void* Wr0 = d_in[4];  const void* br0 = d_in[5];
    const void* att0  = d_in[6];  const void* bias0 = d_in[7];
    const void* Wl1 = d_in[8];  const void* bl1 = d_in[9];
    const void* Wr1 = d_in[10]; const void* br1 = d_in[11];
    const void* att1  = d_in[12]; const void* bias1 = d_in[13];
    const void* Wl2 = d_in[14]; const void* bl2 = d_in[15];
    const void* Wr2 = d_in[16]; const void* br2 = d_in[17];
    const void* att2  = d_in[18]; const void* bias2 = d_in[19];

    // workspace layout (~59.8 MB), f32-slot offsets
    float* ws = (float*)d_ws;
    __hip_bfloat16* hbuf = (__hip_bfloat16*)ws;                  // [N,64] bf16  (1.6M slots)
    __hip_bfloat16* xl2  = (__hip_bfloat16*)(ws + 1600000);      // [N,256] bf16 (6.4M slots)
    __hip_bfloat16* xr2  = (__hip_bfloat16*)(ws + 8000000);      // [N,256] bf16 (6.4M slots)
    __hip_bfloat16* xl   = xl2;                                  // [N,64] bf16 alias (layers 0/1)
    __hip_bfloat16* xr   = (__hip_bfloat16*)(ws + 4800000);      // [N,64] bf16 alias
    int* csr    = (int*)(ws + 14400000);                         // 450k
    int* offs   = csr + 450000;                                  // 50001
    int* counts = offs + 50004;                                  // 50k (reused as cursor)
    int* bsum   = counts + 50000;
    int* bpre   = bsum + 256;
    int* flag   = bpre + 256;

    const int NGE  = cdiv(N_ETOT, 256);
    const int NGW  = cdiv(N_NODES, 4);
    const int NGL  = cdiv(N_NODES, 32);

    detect_kernel<<<1, 256, 0, stream>>>(x, flag);

    // ---- CSR build ----
    hipMemsetAsync(counts, 0, 50000 * 4, stream);
    count_kernel<<<NGE, 256, 0, stream>>>(ei, counts);
    scan_phase1<<<SCAN_BLOCKS, 256, 0, stream>>>(counts, bsum);
    scan_phase2<<<1, 256, 0, stream>>>(bsum, bpre, offs);
    scan_phase3<<<SCAN_BLOCKS, 256, 0, stream>>>(counts, bpre, offs);
    hipMemsetAsync(counts, 0, 50000 * 4, stream);
    fill_kernel<<<NGE, 256, 0, stream>>>(ei, offs, counts, csr);

    // ---- layer 0 ----
    lin_dual_kernel<64, true><<<NGL, 256, 0, stream>>>(x, Wl0, bl0, Wr0, br0, xl, xr, flag);
    gat_fused16_kernel<<<NGW, 256, 0, stream>>>(csr, offs, xl, xr, att0, bias0, hbuf, flag);

    // ---- layer 1 ----
    lin_dual_kernel<64, false><<<NGL, 256, 0, stream>>>(hbuf, Wl1, bl1, Wr1, br1, xl, xr, flag);
    gat_fused16_kernel<<<NGW, 256, 0, stream>>>(csr, offs, xl, xr, att1, bias1, hbuf, flag);

    // ---- layer 2: all heads in one pass, fused mean+bias+store ----
    lin_dual_kernel<256, false><<<NGL, 256, 0, stream>>>(hbuf, Wl2, bl2, Wr2, br2, xl2, xr2, flag);
    gat64x4_kernel<<<N_NODES, 256, 0, stream>>>(csr, offs, xl2, xr2, att2, bias2, d_out, flag);
}

// Round 7
// 429.134 us; speedup vs baseline: 25.7980x; 1.1586x over previous
//
#include <hip/hip_runtime.h>
#include <hip/hip_bf16.h>

#define N_NODES 50000
#define N_EDGES 400000
#define N_ETOT  (N_EDGES + N_NODES)
#define NHEADS  4
#define SCAN_BLOCKS 196   // cdiv(N_NODES, 256)

static constexpr float NEG_SLOPE = 0.2f;
static constexpr float EPS_ = 1e-16f;

__device__ __forceinline__ float b2f(__hip_bfloat16 v) { return __bfloat162float(v); }
__device__ __forceinline__ float ldf(const void* p, long i, int isbf) {
    return isbf ? b2f(((const __hip_bfloat16*)p)[i]) : ((const float*)p)[i];
}
// unpack 8 bf16 (packed in int4) -> 8 f32
__device__ __forceinline__ void unpack8(int4 v, float* f) {
    const unsigned* u = (const unsigned*)&v;
#pragma unroll
    for (int i = 0; i < 4; ++i) {
        f[2 * i]     = __uint_as_float(u[i] << 16);
        f[2 * i + 1] = __uint_as_float(u[i] & 0xffff0000u);
    }
}

// ---------------- dtype detector (proven) ----------------
__global__ __launch_bounds__(256)
void detect_kernel(const void* __restrict__ x, int* __restrict__ flag)
{
    __shared__ int cnt;
    if (threadIdx.x == 0) cnt = 0;
    __syncthreads();
    int local = 0;
    const __hip_bfloat16* p = (const __hip_bfloat16*)x;
    for (int i = threadIdx.x; i < 4096; i += 256) {
        float v = b2f(p[2 * i]);
        if (!(fabsf(v) < 64.f)) local++;
    }
    atomicAdd(&cnt, local);
    __syncthreads();
    if (threadIdx.x == 0) *flag = (cnt < 64) ? 1 : 0;
}

// ---------------- CSR build ----------------
__global__ __launch_bounds__(256)
void count_kernel(const int* __restrict__ ei, int* __restrict__ counts)
{
    const int e = blockIdx.x * 256 + threadIdx.x;
    if (e >= N_ETOT) return;
    const int d = (e < N_EDGES) ? ei[N_EDGES + e] : e - N_EDGES;
    atomicAdd(&counts[d], 1);
}

__global__ __launch_bounds__(256)
void scan_phase1(const int* __restrict__ counts, int* __restrict__ bsum)
{
    __shared__ int sh[256];
    const int idx = blockIdx.x * 256 + threadIdx.x;
    sh[threadIdx.x] = (idx < N_NODES) ? counts[idx] : 0;
    __syncthreads();
    for (int off = 128; off > 0; off >>= 1) {
        if (threadIdx.x < off) sh[threadIdx.x] += sh[threadIdx.x + off];
        __syncthreads();
    }
    if (threadIdx.x == 0) bsum[blockIdx.x] = sh[0];
}

__global__ __launch_bounds__(256)
void scan_phase2(const int* __restrict__ bsum, int* __restrict__ bpre, int* __restrict__ offs)
{
    __shared__ int sh[256];
    const int t = threadIdx.x;
    const int v = (t < SCAN_BLOCKS) ? bsum[t] : 0;
    sh[t] = v;
    __syncthreads();
    for (int off = 1; off < 256; off <<= 1) {
        int u = (t >= off) ? sh[t - off] : 0;
        __syncthreads();
        sh[t] += u;
        __syncthreads();
    }
    if (t < SCAN_BLOCKS) bpre[t] = sh[t] - v;
    if (t == 0) offs[N_NODES] = N_ETOT;
}

__global__ __launch_bounds__(256)
void scan_phase3(const int* __restrict__ counts, const int* __restrict__ bpre,
                 int* __restrict__ offs)
{
    __shared__ int sh[256];
    const int t = threadIdx.x;
    const int idx = blockIdx.x * 256 + t;
    const int v = (idx < N_NODES) ? counts[idx] : 0;
    sh[t] = v;
    __syncthreads();
    for (int off = 1; off < 256; off <<= 1) {
        int u = (t >= off) ? sh[t - off] : 0;
        __syncthreads();
        sh[t] += u;
        __syncthreads();
    }
    if (idx < N_NODES) offs[idx] = bpre[blockIdx.x] + sh[t] - v;
}

__global__ __launch_bounds__(256)
void fill_kernel(const int* __restrict__ ei, const int* __restrict__ offsets,
                 int* __restrict__ cursor, int* __restrict__ csr_src)
{
    const int e = blockIdx.x * 256 + threadIdx.x;
    if (e >= N_ETOT) return;
    int s, d;
    if (e < N_EDGES) { s = ei[e]; d = ei[N_EDGES + e]; } else { s = d = e - N_EDGES; }
    const int pos = atomicAdd(&cursor[d], 1);
    csr_src[offsets[d] + pos] = s;
}

// ---------------- dual linear (layers 0/1): xl/xr[N,64](bf16) ----------------
template<bool EXT>
__global__ __launch_bounds__(256)
void lin_dual_kernel(const void* __restrict__ hin,
                     const void* __restrict__ Wl, const void* __restrict__ bl,
                     const void* __restrict__ Wr, const void* __restrict__ br,
                     __hip_bfloat16* __restrict__ xlp, __hip_bfloat16* __restrict__ xrp,
                     const int* __restrict__ flagp)
{
    constexpr int DOUT = 64;
    const int isbf = *flagp;
    __shared__ __hip_bfloat16 sWl[64 * DOUT];
    __shared__ __hip_bfloat16 sWr[64 * DOUT];
    __shared__ float sh[32][64];
    const int t = threadIdx.x;
    for (int i = t; i < 64 * DOUT; i += 256) {
        sWl[i] = __float2bfloat16(ldf(Wl, i, isbf));
        sWr[i] = __float2bfloat16(ldf(Wr, i, isbf));
    }
    const int row0 = blockIdx.x * 32;
    for (int i = t; i < 32 * 64; i += 256) {
        int r = i >> 6, k = i & 63;
        int rr = row0 + r;
        float v = 0.f;
        if (rr < N_NODES)
            v = EXT ? ldf(hin, (long)rr * 64 + k, isbf)
                    : b2f(((const __hip_bfloat16*)hin)[(long)rr * 64 + k]);
        sh[r][k] = v;
    }
    __syncthreads();

    const int c = t & 63;
    const int r0 = (t >> 6) * 8;
    float accl[8], accr[8];
    const float bvl = ldf(bl, c, isbf);
    const float bvr = ldf(br, c, isbf);
#pragma unroll
    for (int j = 0; j < 8; ++j) { accl[j] = bvl; accr[j] = bvr; }
    for (int k = 0; k < 64; ++k) {
        const float wl = b2f(sWl[k * DOUT + c]);
        const float wr = b2f(sWr[k * DOUT + c]);
#pragma unroll
        for (int j = 0; j < 8; ++j) {
            const float hv = sh[r0 + j][k];
            accl[j] += hv * wl;
            accr[j] += hv * wr;
        }
    }
#pragma unroll
    for (int j = 0; j < 8; ++j) {
        const int rr = row0 + r0 + j;
        if (rr < N_NODES) {
            xlp[(long)rr * DOUT + c] = __float2bfloat16(accl[j]);
            xrp[(long)rr * DOUT + c] = __float2bfloat16(accr[j]);
        }
    }
}

// ---------------- layer-2 linear: 64 rows x 128 cols per block, b128 LDS reads ----------
// grid.y: bit1 = side (0=l, 1=r), bit0 = col-tile (0 or 128). W is [64][256] per side.
__global__ __launch_bounds__(256)
void lin2_kernel(const __hip_bfloat16* __restrict__ hin,
                 const void* __restrict__ Wl, const void* __restrict__ bl,
                 const void* __restrict__ Wr, const void* __restrict__ br,
                 __hip_bfloat16* __restrict__ xlp, __hip_bfloat16* __restrict__ xrp,
                 const int* __restrict__ flagp)
{
    const int isbf = *flagp;
    __shared__ float sh[64 * 64];                 // input rows, f32 [r][k]  (16 KB)
    __shared__ char  sWt[128 * 64 * 2];           // weights bf16 [c][k], XOR-swizzled (16 KB)
    const int t = threadIdx.x;
    const int row0 = blockIdx.x * 64;
    const int side = blockIdx.y >> 1;
    const int col0 = (blockIdx.y & 1) * 128;
    const void* W  = side ? Wr : Wl;
    const void* bb = side ? br : bl;
    __hip_bfloat16* outp = side ? xrp : xlp;

    // stage input rows: 64x64 bf16 -> f32 (vectorized 16B loads)
#pragma unroll
    for (int i = 0; i < 2; ++i) {
        const int chunk = t + i * 256;            // 512 chunks of 8 bf16
        const int r  = chunk >> 3;
        const int k0 = (chunk & 7) * 8;
        const int rr = row0 + r;
        int4 v = make_int4(0, 0, 0, 0);
        if (rr < N_NODES) v = *(const int4*)(hin + (long)rr * 64 + k0);
        float f[8];
        unpack8(v, f);
        float* dst = &sh[r * 64 + k0];
        *(float4*)dst       = make_float4(f[0], f[1], f[2], f[3]);
        *(float4*)(dst + 4) = make_float4(f[4], f[5], f[6], f[7]);
    }
    // stage weights transposed + swizzled: element (k, col0+c) -> sWt[c][k]
#pragma unroll
    for (int i = 0; i < 32; ++i) {
        const int k = (t >> 7) + i * 2;
        const int c = t & 127;
        const float w = ldf(W, (long)k * 256 + col0 + c, isbf);
        const int byteoff = (c * 128 + k * 2) ^ ((c & 7) << 4);
        *(__hip_bfloat16*)(sWt + byteoff) = __float2bfloat16(w);
    }
    __syncthreads();

    const int c = t & 127;
    const int rbase = (t >> 7) * 32;
    float acc[32];
    const float bv = ldf(bb, col0 + c, isbf);
#pragma unroll
    for (int j = 0; j < 32; ++j) acc[j] = bv;

    for (int k8 = 0; k8 < 8; ++k8) {
        const int byteoff = (c * 128 + k8 * 16) ^ ((c & 7) << 4);
        const int4 wv = *(const int4*)(sWt + byteoff);
        float w[8];
        unpack8(wv, w);
#pragma unroll
        for (int j = 0; j < 32; ++j) {
            const float4 s0 = *(const float4*)&sh[(rbase + j) * 64 + k8 * 8];
            const float4 s1 = *(const float4*)&sh[(rbase + j) * 64 + k8 * 8 + 4];
            acc[j] += s0.x * w[0] + s0.y * w[1] + s0.z * w[2] + s0.w * w[3]
                    + s1.x * w[4] + s1.y * w[5] + s1.z * w[6] + s1.w * w[7];
        }
    }
#pragma unroll
    for (int j = 0; j < 32; ++j) {
        const int rr = row0 + rbase + j;
        if (rr < N_NODES) outp[(long)rr * 256 + col0 + c] = __float2bfloat16(acc[j]);
    }
}

// ---------------- fused attention, layers 0/1: wave/node, 2 edges/iter ----------------
__global__ __launch_bounds__(256)
void gat_fused16_kernel(const int* __restrict__ csr_src, const int* __restrict__ offsets,
                        const __hip_bfloat16* __restrict__ xl, const __hip_bfloat16* __restrict__ xr,
                        const void* __restrict__ att, const void* __restrict__ bias,
                        __hip_bfloat16* __restrict__ hout, const int* __restrict__ flagp)
{
    const int isbf = *flagp;
    const int node = blockIdx.x * 4 + (threadIdx.x >> 6);
    if (node >= N_NODES) return;
    const int lane = threadIdx.x & 63;
    const int l32 = lane & 31;
    const int half = lane >> 5;
    const int c0 = l32 * 2;
    const float a0 = ldf(att, c0, isbf), a1 = ldf(att, c0 + 1, isbf);
    const __hip_bfloat162 xr2 = ((const __hip_bfloat162*)(xr + (long)node * 64))[l32];
    const float xr0 = b2f(xr2.x), xr1 = b2f(xr2.y);
    const int beg = offsets[node], end = offsets[node + 1];
    float m = -INFINITY, s = 0.f, acc0 = 0.f, acc1 = 0.f;
    for (int p = beg + half; p < end; p += 2) {
        const int src = csr_src[p];
        const __hip_bfloat162 v2 = ((const __hip_bfloat162*)(xl + (long)src * 64))[l32];
        const float xl0 = b2f(v2.x), xl1 = b2f(v2.y);
        float v0 = xl0 + xr0, v1 = xl1 + xr1;
        v0 = v0 > 0.f ? v0 : NEG_SLOPE * v0;
        v1 = v1 > 0.f ? v1 : NEG_SLOPE * v1;
        float t = v0 * a0 + v1 * a1;
        t += __shfl_xor(t, 1); t += __shfl_xor(t, 2); t += __shfl_xor(t, 4);
        const float mn = fmaxf(m, t);
        const float sc = __expf(m - mn);
        const float w  = __expf(t - mn);
        s = s * sc + w;
        acc0 = acc0 * sc + w * xl0;
        acc1 = acc1 * sc + w * xl1;
        m = mn;
    }
    {
        const float m_p = __shfl_xor(m, 32);
        const float s_p = __shfl_xor(s, 32);
        const float p0  = __shfl_xor(acc0, 32);
        const float p1  = __shfl_xor(acc1, 32);
        const float mm = fmaxf(m, m_p);
        const float e0 = __expf(m - mm), e1 = __expf(m_p - mm);
        s = s * e0 + s_p * e1;
        acc0 = acc0 * e0 + p0 * e1;
        acc1 = acc1 * e0 + p1 * e1;
    }
    float o0 = acc0 / (s + EPS_) + ldf(bias, c0, isbf);
    float o1 = acc1 / (s + EPS_) + ldf(bias, c0 + 1, isbf);
    o0 = o0 > 0.f ? o0 : (__expf(o0) - 1.f);
    o1 = o1 > 0.f ? o1 : (__expf(o1) - 1.f);
    if (half == 0) {
        __hip_bfloat162 ov;
        ov.x = __float2bfloat16(o0); ov.y = __float2bfloat16(o1);
        ((__hip_bfloat162*)(hout + (long)node * 64))[l32] = ov;
    }
}

// ---------------- layer 2: block/node, wave/head, fused head-mean+bias+store ------------
__global__ __launch_bounds__(256)
void gat64x4_kernel(const int* __restrict__ csr_src, const int* __restrict__ offsets,
                    const __hip_bfloat16* __restrict__ xl2, const __hip_bfloat16* __restrict__ xr2,
                    const void* __restrict__ att, const void* __restrict__ bias,
                    void* __restrict__ out, const int* __restrict__ flagp)
{
    const int isbf = *flagp;
    const int node = blockIdx.x;
    const int h = threadIdx.x >> 6;
    const int lane = threadIdx.x & 63;
    const int l32 = lane & 31;
    const int half = lane >> 5;
    const int c0 = l32 * 2;
    __shared__ float sh[NHEADS][64];

    const float a0 = ldf(att, h * 64 + c0, isbf), a1 = ldf(att, h * 64 + c0 + 1, isbf);
    const __hip_bfloat162 xrv = ((const __hip_bfloat162*)(xr2 + (long)node * 256 + h * 64))[l32];
    const float xr0 = b2f(xrv.x), xr1 = b2f(xrv.y);
    const int beg = offsets[node], end = offsets[node + 1];
    float m = -INFINITY, s = 0.f, acc0 = 0.f, acc1 = 0.f;
    for (int p = beg + half; p < end; p += 2) {
        const int src = csr_src[p];
        const __hip_bfloat162 v2 = ((const __hip_bfloat162*)(xl2 + (long)src * 256 + h * 64))[l32];
        const float xl0 = b2f(v2.x), xl1 = b2f(v2.y);
        float v0 = xl0 + xr0, v1 = xl1 + xr1;
        v0 = v0 > 0.f ? v0 : NEG_SLOPE * v0;
        v1 = v1 > 0.f ? v1 : NEG_SLOPE * v1;
        float t = v0 * a0 + v1 * a1;
        t += __shfl_xor(t, 1); t += __shfl_xor(t, 2); t += __shfl_xor(t, 4);
        t += __shfl_xor(t, 8); t += __shfl_xor(t, 16);
        const float mn = fmaxf(m, t);
        const float sc = __expf(m - mn);
        const float w  = __expf(t - mn);
        s = s * sc + w;
        acc0 = acc0 * sc + w * xl0;
        acc1 = acc1 * sc + w * xl1;
        m = mn;
    }
    {
        const float m_p = __shfl_xor(m, 32);
        const float s_p = __shfl_xor(s, 32);
        const float p0  = __shfl_xor(acc0, 32);
        const float p1  = __shfl_xor(acc1, 32);
        const float mm = fmaxf(m, m_p);
        const float e0 = __expf(m - mm), e1 = __expf(m_p - mm);
        s = s * e0 + s_p * e1;
        acc0 = acc0 * e0 + p0 * e1;
        acc1 = acc1 * e0 + p1 * e1;
    }
    if (half == 0) {
        sh[h][c0]     = acc0 / (s + EPS_);
        sh[h][c0 + 1] = acc1 / (s + EPS_);
    }
    __syncthreads();
    if (threadIdx.x < 64) {
        const int d = threadIdx.x;
        const float v = (sh[0][d] + sh[1][d] + sh[2][d] + sh[3][d]) * 0.25f
                        + ldf(bias, d, isbf);
        if (isbf) ((__hip_bfloat16*)out)[(long)node * 64 + d] = __float2bfloat16(v);
        else      ((float*)out)[(long)node * 64 + d] = v;
    }
}

static inline int cdiv(int a, int b) { return (a + b - 1) / b; }

extern "C" void kernel_launch(void* const* d_in, const int* in_sizes, int n_in,
                              void* d_out, int out_size, void* d_ws, size_t ws_size,
                              hipStream_t stream)
{
    const void* x   = d_in[0];
    const int*  ei  = (const int*)d_in[1];
    const void* Wl0 = d_in[2];  const void* bl0 = d_in[3];
    const void* Wr0 = d_in[4];  const void* br0 = d_in[5];
    const void* att0  = d_in[6];  const void* bias0 = d_in[7];
    const void* Wl1 = d_in[8];  const void* bl1 = d_in[9];
    const void* Wr1 = d_in[10]; const void* br1 = d_in[11];
    const void* att1  = d_in[12]; const void* bias1 = d_in[13];
    const void* Wl2 = d_in[14]; const void* bl2 = d_in[15];
    const void* Wr2 = d_in[16]; const void* br2 = d_in[17];
    const void* att2  = d_in[18]; const void* bias2 = d_in[19];

    // workspace layout (~59.8 MB), f32-slot offsets
    float* ws = (float*)d_ws;
    __hip_bfloat16* hbuf = (__hip_bfloat16*)ws;                  // [N,64] bf16
    __hip_bfloat16* xl2  = (__hip_bfloat16*)(ws + 1600000);      // [N,256] bf16
    __hip_bfloat16* xr2  = (__hip_bfloat16*)(ws + 8000000);      // [N,256] bf16
    __hip_bfloat16* xl   = xl2;                                  // [N,64] alias (layers 0/1)
    __hip_bfloat16* xr   = (__hip_bfloat16*)(ws + 4800000);      // [N,64] alias
    int* csr    = (int*)(ws + 14400000);                         // 450k
    int* offs   = csr + 450000;                                  // 50001
    int* counts = offs + 50004;                                  // 50k (reused as cursor)
    int* bsum   = counts + 50000;
    int* bpre   = bsum + 256;
    int* flag   = bpre + 256;

    const int NGE = cdiv(N_ETOT, 256);
    const int NGW = cdiv(N_NODES, 4);
    const int NGL = cdiv(N_NODES, 32);

    detect_kernel<<<1, 256, 0, stream>>>(x, flag);

    // ---- CSR build ----
    hipMemsetAsync(counts, 0, 50000 * 4, stream);
    count_kernel<<<NGE, 256, 0, stream>>>(ei, counts);
    scan_phase1<<<SCAN_BLOCKS, 256, 0, stream>>>(counts, bsum);
    scan_phase2<<<1, 256, 0, stream>>>(bsum, bpre, offs);
    scan_phase3<<<SCAN_BLOCKS, 256, 0, stream>>>(counts, bpre, offs);
    hipMemsetAsync(counts, 0, 50000 * 4, stream);
    fill_kernel<<<NGE, 256, 0, stream>>>(ei, offs, counts, csr);

    // ---- layer 0 ----
    lin_dual_kernel<true><<<NGL, 256, 0, stream>>>(x, Wl0, bl0, Wr0, br0, xl, xr, flag);
    gat_fused16_kernel<<<NGW, 256, 0, stream>>>(csr, offs, xl, xr, att0, bias0, hbuf, flag);

    // ---- layer 1 ----
    lin_dual_kernel<false><<<NGL, 256, 0, stream>>>(hbuf, Wl1, bl1, Wr1, br1, xl, xr, flag);
    gat_fused16_kernel<<<NGW, 256, 0, stream>>>(csr, offs, xl, xr, att1, bias1, hbuf, flag);

    // ---- layer 2: fast linear, then all heads in one pass ----
    {
        dim3 g2(cdiv(N_NODES, 64), 4);
        lin2_kernel<<<g2, 256, 0, stream>>>(hbuf, Wl2, bl2, Wr2, br2, xl2, xr2, flag);
    }
    gat64x4_kernel<<<N_NODES, 256, 0, stream>>>(csr, offs, xl2, xr2, att2, bias2, d_out, flag);
}

// Round 8
// 370.149 us; speedup vs baseline: 29.9090x; 1.1594x over previous
//
#include <hip/hip_runtime.h>
#include <hip/hip_bf16.h>

#define N_NODES 50000
#define N_EDGES 400000
#define N_ETOT  (N_EDGES + N_NODES)
#define NHEADS  4
#define SCAN_BLOCKS 196   // cdiv(N_NODES, 256)

static constexpr float NEG_SLOPE = 0.2f;
static constexpr float EPS_ = 1e-16f;
static constexpr float NEG_BIG = -1e30f;   // NaN-free empty-segment sentinel

__device__ __forceinline__ float b2f(__hip_bfloat16 v) { return __bfloat162float(v); }
__device__ __forceinline__ float ldf(const void* p, long i, int isbf) {
    return isbf ? b2f(((const __hip_bfloat16*)p)[i]) : ((const float*)p)[i];
}
__device__ __forceinline__ void unpack8(int4 v, float* f) {
    const unsigned* u = (const unsigned*)&v;
#pragma unroll
    for (int i = 0; i < 4; ++i) {
        f[2 * i]     = __uint_as_float(u[i] << 16);
        f[2 * i + 1] = __uint_as_float(u[i] & 0xffff0000u);
    }
}
__device__ __forceinline__ void unpack4(int2 v, float* f) {
    const unsigned* u = (const unsigned*)&v;
    f[0] = __uint_as_float(u[0] << 16);
    f[1] = __uint_as_float(u[0] & 0xffff0000u);
    f[2] = __uint_as_float(u[1] << 16);
    f[3] = __uint_as_float(u[1] & 0xffff0000u);
}

// ---------------- dtype detector + counts zeroing (fused) ----------------
__global__ __launch_bounds__(256)
void detect_zero_kernel(const void* __restrict__ x, int* __restrict__ flag,
                        int* __restrict__ counts)
{
    const int idx = blockIdx.x * 256 + threadIdx.x;
    if (idx < N_NODES) counts[idx] = 0;
    if (blockIdx.x != 0) return;
    __shared__ int cnt;
    if (threadIdx.x == 0) cnt = 0;
    __syncthreads();
    int local = 0;
    const __hip_bfloat16* p = (const __hip_bfloat16*)x;
    for (int i = threadIdx.x; i < 4096; i += 256) {
        float v = b2f(p[2 * i]);
        if (!(fabsf(v) < 64.f)) local++;
    }
    atomicAdd(&cnt, local);
    __syncthreads();
    if (threadIdx.x == 0) *flag = (cnt < 64) ? 1 : 0;
}

// ---------------- CSR build ----------------
__global__ __launch_bounds__(256)
void count_kernel(const int* __restrict__ ei, int* __restrict__ counts)
{
    const int e = blockIdx.x * 256 + threadIdx.x;
    if (e >= N_ETOT) return;
    const int d = (e < N_EDGES) ? ei[N_EDGES + e] : e - N_EDGES;
    atomicAdd(&counts[d], 1);
}

__global__ __launch_bounds__(256)
void scan_phase1(const int* __restrict__ counts, int* __restrict__ bsum)
{
    __shared__ int sh[256];
    const int idx = blockIdx.x * 256 + threadIdx.x;
    sh[threadIdx.x] = (idx < N_NODES) ? counts[idx] : 0;
    __syncthreads();
    for (int off = 128; off > 0; off >>= 1) {
        if (threadIdx.x < off) sh[threadIdx.x] += sh[threadIdx.x + off];
        __syncthreads();
    }
    if (threadIdx.x == 0) bsum[blockIdx.x] = sh[0];
}

__global__ __launch_bounds__(256)
void scan_phase2(const int* __restrict__ bsum, int* __restrict__ bpre, int* __restrict__ offs)
{
    __shared__ int sh[256];
    const int t = threadIdx.x;
    const int v = (t < SCAN_BLOCKS) ? bsum[t] : 0;
    sh[t] = v;
    __syncthreads();
    for (int off = 1; off < 256; off <<= 1) {
        int u = (t >= off) ? sh[t - off] : 0;
        __syncthreads();
        sh[t] += u;
        __syncthreads();
    }
    if (t < SCAN_BLOCKS) bpre[t] = sh[t] - v;
    if (t == 0) offs[N_NODES] = N_ETOT;
}

// also initializes cursor[] = offs[] (absolute fill positions; saves a memset)
__global__ __launch_bounds__(256)
void scan_phase3(int* __restrict__ counts, const int* __restrict__ bpre,
                 int* __restrict__ offs)
{
    __shared__ int sh[256];
    const int t = threadIdx.x;
    const int idx = blockIdx.x * 256 + t;
    const int v = (idx < N_NODES) ? counts[idx] : 0;
    sh[t] = v;
    __syncthreads();
    for (int off = 1; off < 256; off <<= 1) {
        int u = (t >= off) ? sh[t - off] : 0;
        __syncthreads();
        sh[t] += u;
        __syncthreads();
    }
    if (idx < N_NODES) {
        const int o = bpre[blockIdx.x] + sh[t] - v;
        offs[idx] = o;
        counts[idx] = o;      // counts becomes the fill cursor
    }
}

__global__ __launch_bounds__(256)
void fill_kernel(const int* __restrict__ ei, int* __restrict__ cursor,
                 int* __restrict__ csr_src)
{
    const int e = blockIdx.x * 256 + threadIdx.x;
    if (e >= N_ETOT) return;
    int s, d;
    if (e < N_EDGES) { s = ei[e]; d = ei[N_EDGES + e]; } else { s = d = e - N_EDGES; }
    const int pos = atomicAdd(&cursor[d], 1);
    csr_src[pos] = s;
}

// ---------------- dual linear (layers 0/1): xl/xr[N,64](bf16) ----------------
template<bool EXT>
__global__ __launch_bounds__(256)
void lin_dual_kernel(const void* __restrict__ hin,
                     const void* __restrict__ Wl, const void* __restrict__ bl,
                     const void* __restrict__ Wr, const void* __restrict__ br,
                     __hip_bfloat16* __restrict__ xlp, __hip_bfloat16* __restrict__ xrp,
                     const int* __restrict__ flagp)
{
    constexpr int DOUT = 64;
    const int isbf = *flagp;
    __shared__ __hip_bfloat16 sWl[64 * DOUT];
    __shared__ __hip_bfloat16 sWr[64 * DOUT];
    __shared__ float sh[32][64];
    const int t = threadIdx.x;
    for (int i = t; i < 64 * DOUT; i += 256) {
        sWl[i] = __float2bfloat16(ldf(Wl, i, isbf));
        sWr[i] = __float2bfloat16(ldf(Wr, i, isbf));
    }
    const int row0 = blockIdx.x * 32;
    for (int i = t; i < 32 * 64; i += 256) {
        int r = i >> 6, k = i & 63;
        int rr = row0 + r;
        float v = 0.f;
        if (rr < N_NODES)
            v = EXT ? ldf(hin, (long)rr * 64 + k, isbf)
                    : b2f(((const __hip_bfloat16*)hin)[(long)rr * 64 + k]);
        sh[r][k] = v;
    }
    __syncthreads();

    const int c = t & 63;
    const int r0 = (t >> 6) * 8;
    float accl[8], accr[8];
    const float bvl = ldf(bl, c, isbf);
    const float bvr = ldf(br, c, isbf);
#pragma unroll
    for (int j = 0; j < 8; ++j) { accl[j] = bvl; accr[j] = bvr; }
    for (int k = 0; k < 64; ++k) {
        const float wl = b2f(sWl[k * DOUT + c]);
        const float wr = b2f(sWr[k * DOUT + c]);
#pragma unroll
        for (int j = 0; j < 8; ++j) {
            const float hv = sh[r0 + j][k];
            accl[j] += hv * wl;
            accr[j] += hv * wr;
        }
    }
#pragma unroll
    for (int j = 0; j < 8; ++j) {
        const int rr = row0 + r0 + j;
        if (rr < N_NODES) {
            xlp[(long)rr * DOUT + c] = __float2bfloat16(accl[j]);
            xrp[(long)rr * DOUT + c] = __float2bfloat16(accr[j]);
        }
    }
}

// ---------------- layer-2 linear: 64 rows x 128 cols per block, b128 LDS reads ----------
__global__ __launch_bounds__(256)
void lin2_kernel(const __hip_bfloat16* __restrict__ hin,
                 const void* __restrict__ Wl, const void* __restrict__ bl,
                 const void* __restrict__ Wr, const void* __restrict__ br,
                 __hip_bfloat16* __restrict__ xlp, __hip_bfloat16* __restrict__ xrp,
                 const int* __restrict__ flagp)
{
    const int isbf = *flagp;
    __shared__ float sh[64 * 64];
    __shared__ char  sWt[128 * 64 * 2];
    const int t = threadIdx.x;
    const int row0 = blockIdx.x * 64;
    const int side = blockIdx.y >> 1;
    const int col0 = (blockIdx.y & 1) * 128;
    const void* W  = side ? Wr : Wl;
    const void* bb = side ? br : bl;
    __hip_bfloat16* outp = side ? xrp : xlp;

#pragma unroll
    for (int i = 0; i < 2; ++i) {
        const int chunk = t + i * 256;
        const int r  = chunk >> 3;
        const int k0 = (chunk & 7) * 8;
        const int rr = row0 + r;
        int4 v = make_int4(0, 0, 0, 0);
        if (rr < N_NODES) v = *(const int4*)(hin + (long)rr * 64 + k0);
        float f[8];
        unpack8(v, f);
        float* dst = &sh[r * 64 + k0];
        *(float4*)dst       = make_float4(f[0], f[1], f[2], f[3]);
        *(float4*)(dst + 4) = make_float4(f[4], f[5], f[6], f[7]);
    }
#pragma unroll
    for (int i = 0; i < 32; ++i) {
        const int k = (t >> 7) + i * 2;
        const int c = t & 127;
        const float w = ldf(W, (long)k * 256 + col0 + c, isbf);
        const int byteoff = (c * 128 + k * 2) ^ ((c & 7) << 4);
        *(__hip_bfloat16*)(sWt + byteoff) = __float2bfloat16(w);
    }
    __syncthreads();

    const int c = t & 127;
    const int rbase = (t >> 7) * 32;
    float acc[32];
    const float bv = ldf(bb, col0 + c, isbf);
#pragma unroll
    for (int j = 0; j < 32; ++j) acc[j] = bv;

    for (int k8 = 0; k8 < 8; ++k8) {
        const int byteoff = (c * 128 + k8 * 16) ^ ((c & 7) << 4);
        const int4 wv = *(const int4*)(sWt + byteoff);
        float w[8];
        unpack8(wv, w);
#pragma unroll
        for (int j = 0; j < 32; ++j) {
            const float4 s0 = *(const float4*)&sh[(rbase + j) * 64 + k8 * 8];
            const float4 s1 = *(const float4*)&sh[(rbase + j) * 64 + k8 * 8 + 4];
            acc[j] += s0.x * w[0] + s0.y * w[1] + s0.z * w[2] + s0.w * w[3]
                    + s1.x * w[4] + s1.y * w[5] + s1.z * w[6] + s1.w * w[7];
        }
    }
#pragma unroll
    for (int j = 0; j < 32; ++j) {
        const int rr = row0 + rbase + j;
        if (rr < N_NODES) outp[(long)rr * 256 + col0 + c] = __float2bfloat16(acc[j]);
    }
}

// ---------------- fused attention, layers 0/1: 16 lanes/edge, 4 edges/wave/iter ----------
__global__ __launch_bounds__(256)
void gat_fused16_kernel(const int* __restrict__ csr_src, const int* __restrict__ offsets,
                        const __hip_bfloat16* __restrict__ xl, const __hip_bfloat16* __restrict__ xr,
                        const void* __restrict__ att, const void* __restrict__ bias,
                        __hip_bfloat16* __restrict__ hout, const int* __restrict__ flagp)
{
    const int isbf = *flagp;
    const int node = blockIdx.x * 4 + (threadIdx.x >> 6);
    if (node >= N_NODES) return;
    const int lane = threadIdx.x & 63;
    const int l16 = lane & 15;            // lane covers channels l16*4 .. +4 (head = l16>>2)
    const int q = lane >> 4;              // quarter handles edges p ≡ q (mod 4)
    float a[4], xrv[4];
    {
        const int2 v = *(const int2*)(xr + (long)node * 64 + l16 * 4);
        unpack4(v, xrv);
#pragma unroll
        for (int j = 0; j < 4; ++j) a[j] = ldf(att, l16 * 4 + j, isbf);
    }
    const int beg = offsets[node], end = offsets[node + 1];
    float m = NEG_BIG, s = 0.f, acc[4] = {0.f, 0.f, 0.f, 0.f};
    for (int p = beg + q; p < end; p += 4) {
        const int src = csr_src[p];
        const int2 v = *(const int2*)(xl + (long)src * 64 + l16 * 4);
        float xlv[4]; unpack4(v, xlv);
        float t = 0.f;
#pragma unroll
        for (int j = 0; j < 4; ++j) {
            float u = xlv[j] + xrv[j];
            u = u > 0.f ? u : NEG_SLOPE * u;
            t += u * a[j];
        }
        t += __shfl_xor(t, 1); t += __shfl_xor(t, 2);   // 16-ch head dot (4 lanes)
        const float mn = fmaxf(m, t);
        const float sc = __expf(m - mn);
        const float w  = __expf(t - mn);
        s = s * sc + w;
#pragma unroll
        for (int j = 0; j < 4; ++j) acc[j] = acc[j] * sc + w * xlv[j];
        m = mn;
    }
    // merge 4 quarter-states (NaN-free via NEG_BIG sentinel)
#pragma unroll
    for (int step = 16; step <= 32; step <<= 1) {
        const float m_p = __shfl_xor(m, step);
        const float s_p = __shfl_xor(s, step);
        const float mm = fmaxf(m, m_p);
        const float e0 = __expf(m - mm), e1 = __expf(m_p - mm);
        s = s * e0 + s_p * e1;
#pragma unroll
        for (int j = 0; j < 4; ++j) {
            const float ap = __shfl_xor(acc[j], step);
            acc[j] = acc[j] * e0 + ap * e1;
        }
        m = mm;
    }
    if (q == 0) {
        __hip_bfloat16 ob[4];
#pragma unroll
        for (int j = 0; j < 4; ++j) {
            float o = acc[j] / (s + EPS_) + ldf(bias, l16 * 4 + j, isbf);
            o = o > 0.f ? o : (__expf(o) - 1.f);   // ELU
            ob[j] = __float2bfloat16(o);
        }
        *(int2*)(hout + (long)node * 64 + l16 * 4) = *(int2*)ob;
    }
}

// ---------------- layer 2: all 4 heads per edge, half-wave/edge, fused mean+bias ---------
__global__ __launch_bounds__(256)
void gat256_kernel(const int* __restrict__ csr_src, const int* __restrict__ offsets,
                   const __hip_bfloat16* __restrict__ xl2, const __hip_bfloat16* __restrict__ xr2,
                   const void* __restrict__ att, const void* __restrict__ bias,
                   void* __restrict__ out, const int* __restrict__ flagp)
{
    const int isbf = *flagp;
    const int node = blockIdx.x * 4 + (threadIdx.x >> 6);
    if (node >= N_NODES) return;
    const int lane = threadIdx.x & 63;
    const int l32 = lane & 31;            // covers global channels l32*8 .. +8 (head = l32>>3)
    const int half = lane >> 5;
    float a[8], xrv[8];
    {
        const int4 v = *(const int4*)(xr2 + (long)node * 256 + l32 * 8);
        unpack8(v, xrv);
#pragma unroll
        for (int j = 0; j < 8; ++j) a[j] = ldf(att, l32 * 8 + j, isbf);
    }
    const int beg = offsets[node], end = offsets[node + 1];
    float m = NEG_BIG, s = 0.f;
    float acc[8] = {0.f, 0.f, 0.f, 0.f, 0.f, 0.f, 0.f, 0.f};
    for (int p = beg + half; p < end; p += 2) {
        const int src = csr_src[p];
        const int4 v = *(const int4*)(xl2 + (long)src * 256 + l32 * 8);  // 512B/edge, one visit
        float xlv[8]; unpack8(v, xlv);
        float t = 0.f;
#pragma unroll
        for (int j = 0; j < 8; ++j) {
            float u = xlv[j] + xrv[j];
            u = u > 0.f ? u : NEG_SLOPE * u;
            t += u * a[j];
        }
        t += __shfl_xor(t, 1); t += __shfl_xor(t, 2); t += __shfl_xor(t, 4);  // 64-ch head dot
        const float mn = fmaxf(m, t);
        const float sc = __expf(m - mn);
        const float w  = __expf(t - mn);
        s = s * sc + w;
#pragma unroll
        for (int j = 0; j < 8; ++j) acc[j] = acc[j] * sc + w * xlv[j];
        m = mn;
    }
    // merge the two half-wave states
    {
        const float m_p = __shfl_xor(m, 32);
        const float s_p = __shfl_xor(s, 32);
        const float mm = fmaxf(m, m_p);
        const float e0 = __expf(m - mm), e1 = __expf(m_p - mm);
        s = s * e0 + s_p * e1;
#pragma unroll
        for (int j = 0; j < 8; ++j) {
            const float ap = __shfl_xor(acc[j], 32);
            acc[j] = acc[j] * e0 + ap * e1;
        }
    }
    const float inv = 1.f / (s + EPS_);
#pragma unroll
    for (int j = 0; j < 8; ++j) acc[j] *= inv;
    // head mean: butterfly over head bits (3,4) of l32; channel block (l32&7) preserved
#pragma unroll
    for (int j = 0; j < 8; ++j) {
        acc[j] += __shfl_xor(acc[j], 8);
        acc[j] += __shfl_xor(acc[j], 16);
        acc[j] *= 0.25f;
    }
    if (lane < 8) {
        const int c0 = lane * 8;
        if (isbf) {
            __hip_bfloat16 ob[8];
#pragma unroll
            for (int j = 0; j < 8; ++j)
                ob[j] = __float2bfloat16(acc[j] + ldf(bias, c0 + j, isbf));
            *(int4*)((__hip_bfloat16*)out + (long)node * 64 + c0) = *(const int4*)ob;
        } else {
            float* po = (float*)out + (long)node * 64 + c0;
#pragma unroll
            for (int j = 0; j < 8; ++j) po[j] = acc[j] + ldf(bias, c0 + j, isbf);
        }
    }
}

static inline int cdiv(int a, int b) { return (a + b - 1) / b; }

extern "C" void kernel_launch(void* const* d_in, const int* in_sizes, int n_in,
                              void* d_out, int out_size, void* d_ws, size_t ws_size,
                              hipStream_t stream)
{
    const void* x   = d_in[0];
    const int*  ei  = (const int*)d_in[1];
    const void* Wl0 = d_in[2];  const void* bl0 = d_in[3];
    const void* Wr0 = d_in[4];  const void* br0 = d_in[5];
    const void* att0  = d_in[6];  const void* bias0 = d_in[7];
    const void* Wl1 = d_in[8];  const void* bl1 = d_in[9];
    const void* Wr1 = d_in[10]; const void* br1 = d_in[11];
    const void* att1  = d_in[12]; const void* bias1 = d_in[13];
    const void* Wl2 = d_in[14]; const void* bl2 = d_in[15];
    const void* Wr2 = d_in[16]; const void* br2 = d_in[17];
    const void* att2  = d_in[18]; const void* bias2 = d_in[19];

    // workspace layout (~59.8 MB), f32-slot offsets
    float* ws = (float*)d_ws;
    __hip_bfloat16* hbuf = (__hip_bfloat16*)ws;                  // [N,64] bf16
    __hip_bfloat16* xl2  = (__hip_bfloat16*)(ws + 1600000);      // [N,256] bf16
    __hip_bfloat16* xr2  = (__hip_bfloat16*)(ws + 8000000);      // [N,256] bf16
    __hip_bfloat16* xl   = xl2;                                  // [N,64] alias (layers 0/1)
    __hip_bfloat16* xr   = (__hip_bfloat16*)(ws + 4800000);      // [N,64] alias
    int* csr    = (int*)(ws + 14400000);                         // 450k
    int* offs   = csr + 450000;                                  // 50001
    int* counts = offs + 50004;                                  // 50k (doubles as fill cursor)
    int* bsum   = counts + 50000;
    int* bpre   = bsum + 256;
    int* flag   = bpre + 256;

    const int NGE = cdiv(N_ETOT, 256);
    const int NGW = cdiv(N_NODES, 4);
    const int NGL = cdiv(N_NODES, 32);

    // ---- CSR build (no memsets: zeroing/cursor folded into kernels) ----
    detect_zero_kernel<<<SCAN_BLOCKS, 256, 0, stream>>>(x, flag, counts);
    count_kernel<<<NGE, 256, 0, stream>>>(ei, counts);
    scan_phase1<<<SCAN_BLOCKS, 256, 0, stream>>>(counts, bsum);
    scan_phase2<<<1, 256, 0, stream>>>(bsum, bpre, offs);
    scan_phase3<<<SCAN_BLOCKS, 256, 0, stream>>>(counts, bpre, offs);
    fill_kernel<<<NGE, 256, 0, stream>>>(ei, counts, csr);

    // ---- layer 0 ----
    lin_dual_kernel<true><<<NGL, 256, 0, stream>>>(x, Wl0, bl0, Wr0, br0, xl, xr, flag);
    gat_fused16_kernel<<<NGW, 256, 0, stream>>>(csr, offs, xl, xr, att0, bias0, hbuf, flag);

    // ---- layer 1 ----
    lin_dual_kernel<false><<<NGL, 256, 0, stream>>>(hbuf, Wl1, bl1, Wr1, br1, xl, xr, flag);
    gat_fused16_kernel<<<NGW, 256, 0, stream>>>(csr, offs, xl, xr, att1, bias1, hbuf, flag);

    // ---- layer 2: fast linear, then one all-heads pass ----
    {
        dim3 g2(cdiv(N_NODES, 64), 4);
        lin2_kernel<<<g2, 256, 0, stream>>>(hbuf, Wl2, bl2, Wr2, br2, xl2, xr2, flag);
    }
    gat256_kernel<<<NGW, 256, 0, stream>>>(csr, offs, xl2, xr2, att2, bias2, d_out, flag);
}

// Round 9
// 370.068 us; speedup vs baseline: 29.9155x; 1.0002x over previous
//
#include <hip/hip_runtime.h>
#include <hip/hip_bf16.h>

#define N_NODES 50000
#define N_EDGES 400000
#define N_ETOT  (N_EDGES + N_NODES)
#define NHEADS  4
#define SCAN_BLOCKS 196   // cdiv(N_NODES, 256)

static constexpr float NEG_SLOPE = 0.2f;
static constexpr float EPS_ = 1e-16f;
static constexpr float NEG_BIG = -1e30f;   // NaN-free empty-segment sentinel

__device__ __forceinline__ float b2f(__hip_bfloat16 v) { return __bfloat162float(v); }
__device__ __forceinline__ float ldf(const void* p, long i, int isbf) {
    return isbf ? b2f(((const __hip_bfloat16*)p)[i]) : ((const float*)p)[i];
}
__device__ __forceinline__ void unpack8(int4 v, float* f) {
    const unsigned* u = (const unsigned*)&v;
#pragma unroll
    for (int i = 0; i < 4; ++i) {
        f[2 * i]     = __uint_as_float(u[i] << 16);
        f[2 * i + 1] = __uint_as_float(u[i] & 0xffff0000u);
    }
}
__device__ __forceinline__ void unpack4(int2 v, float* f) {
    const unsigned* u = (const unsigned*)&v;
    f[0] = __uint_as_float(u[0] << 16);
    f[1] = __uint_as_float(u[0] & 0xffff0000u);
    f[2] = __uint_as_float(u[1] << 16);
    f[3] = __uint_as_float(u[1] & 0xffff0000u);
}

// ---------------- dtype detector + counts zeroing (fused) ----------------
__global__ __launch_bounds__(256)
void detect_zero_kernel(const void* __restrict__ x, int* __restrict__ flag,
                        int* __restrict__ counts)
{
    const int idx = blockIdx.x * 256 + threadIdx.x;
    if (idx < N_NODES) counts[idx] = 0;
    if (blockIdx.x != 0) return;
    __shared__ int cnt;
    if (threadIdx.x == 0) cnt = 0;
    __syncthreads();
    int local = 0;
    const __hip_bfloat16* p = (const __hip_bfloat16*)x;
    for (int i = threadIdx.x; i < 4096; i += 256) {
        float v = b2f(p[2 * i]);
        if (!(fabsf(v) < 64.f)) local++;
    }
    atomicAdd(&cnt, local);
    __syncthreads();
    if (threadIdx.x == 0) *flag = (cnt < 64) ? 1 : 0;
}

// ---------------- CSR build ----------------
__global__ __launch_bounds__(256)
void count_kernel(const int* __restrict__ ei, int* __restrict__ counts)
{
    const int e = blockIdx.x * 256 + threadIdx.x;
    if (e >= N_ETOT) return;
    const int d = (e < N_EDGES) ? ei[N_EDGES + e] : e - N_EDGES;
    atomicAdd(&counts[d], 1);
}

__global__ __launch_bounds__(256)
void scan_phase1(const int* __restrict__ counts, int* __restrict__ bsum)
{
    __shared__ int sh[256];
    const int idx = blockIdx.x * 256 + threadIdx.x;
    sh[threadIdx.x] = (idx < N_NODES) ? counts[idx] : 0;
    __syncthreads();
    for (int off = 128; off > 0; off >>= 1) {
        if (threadIdx.x < off) sh[threadIdx.x] += sh[threadIdx.x + off];
        __syncthreads();
    }
    if (threadIdx.x == 0) bsum[blockIdx.x] = sh[0];
}

__global__ __launch_bounds__(256)
void scan_phase2(const int* __restrict__ bsum, int* __restrict__ bpre, int* __restrict__ offs)
{
    __shared__ int sh[256];
    const int t = threadIdx.x;
    const int v = (t < SCAN_BLOCKS) ? bsum[t] : 0;
    sh[t] = v;
    __syncthreads();
    for (int off = 1; off < 256; off <<= 1) {
        int u = (t >= off) ? sh[t - off] : 0;
        __syncthreads();
        sh[t] += u;
        __syncthreads();
    }
    if (t < SCAN_BLOCKS) bpre[t] = sh[t] - v;
    if (t == 0) offs[N_NODES] = N_ETOT;
}

// also initializes cursor[] = offs[] (absolute fill positions; saves a memset)
__global__ __launch_bounds__(256)
void scan_phase3(int* __restrict__ counts, const int* __restrict__ bpre,
                 int* __restrict__ offs)
{
    __shared__ int sh[256];
    const int t = threadIdx.x;
    const int idx = blockIdx.x * 256 + t;
    const int v = (idx < N_NODES) ? counts[idx] : 0;
    sh[t] = v;
    __syncthreads();
    for (int off = 1; off < 256; off <<= 1) {
        int u = (t >= off) ? sh[t - off] : 0;
        __syncthreads();
        sh[t] += u;
        __syncthreads();
    }
    if (idx < N_NODES) {
        const int o = bpre[blockIdx.x] + sh[t] - v;
        offs[idx] = o;
        counts[idx] = o;      // counts becomes the fill cursor
    }
}

__global__ __launch_bounds__(256)
void fill_kernel(const int* __restrict__ ei, int* __restrict__ cursor,
                 int* __restrict__ csr_src)
{
    const int e = blockIdx.x * 256 + threadIdx.x;
    if (e >= N_ETOT) return;
    int s, d;
    if (e < N_EDGES) { s = ei[e]; d = ei[N_EDGES + e]; } else { s = d = e - N_EDGES; }
    const int pos = atomicAdd(&cursor[d], 1);
    csr_src[pos] = s;
}

// ---------------- dual linear (layers 0/1): xl/xr[N,64](bf16) ----------------
template<bool EXT>
__global__ __launch_bounds__(256)
void lin_dual_kernel(const void* __restrict__ hin,
                     const void* __restrict__ Wl, const void* __restrict__ bl,
                     const void* __restrict__ Wr, const void* __restrict__ br,
                     __hip_bfloat16* __restrict__ xlp, __hip_bfloat16* __restrict__ xrp,
                     const int* __restrict__ flagp)
{
    constexpr int DOUT = 64;
    const int isbf = *flagp;
    __shared__ __hip_bfloat16 sWl[64 * DOUT];
    __shared__ __hip_bfloat16 sWr[64 * DOUT];
    __shared__ float sh[32][64];
    const int t = threadIdx.x;
    for (int i = t; i < 64 * DOUT; i += 256) {
        sWl[i] = __float2bfloat16(ldf(Wl, i, isbf));
        sWr[i] = __float2bfloat16(ldf(Wr, i, isbf));
    }
    const int row0 = blockIdx.x * 32;
    for (int i = t; i < 32 * 64; i += 256) {
        int r = i >> 6, k = i & 63;
        int rr = row0 + r;
        float v = 0.f;
        if (rr < N_NODES)
            v = EXT ? ldf(hin, (long)rr * 64 + k, isbf)
                    : b2f(((const __hip_bfloat16*)hin)[(long)rr * 64 + k]);
        sh[r][k] = v;
    }
    __syncthreads();

    const int c = t & 63;
    const int r0 = (t >> 6) * 8;
    float accl[8], accr[8];
    const float bvl = ldf(bl, c, isbf);
    const float bvr = ldf(br, c, isbf);
#pragma unroll
    for (int j = 0; j < 8; ++j) { accl[j] = bvl; accr[j] = bvr; }
    for (int k = 0; k < 64; ++k) {
        const float wl = b2f(sWl[k * DOUT + c]);
        const float wr = b2f(sWr[k * DOUT + c]);
#pragma unroll
        for (int j = 0; j < 8; ++j) {
            const float hv = sh[r0 + j][k];
            accl[j] += hv * wl;
            accr[j] += hv * wr;
        }
    }
#pragma unroll
    for (int j = 0; j < 8; ++j) {
        const int rr = row0 + r0 + j;
        if (rr < N_NODES) {
            xlp[(long)rr * DOUT + c] = __float2bfloat16(accl[j]);
            xrp[(long)rr * DOUT + c] = __float2bfloat16(accr[j]);
        }
    }
}

// ---------------- layer-2 linear: 64 rows x 128 cols per block, b128 LDS reads ----------
// grid.y: bit1 = side (0=l, 1=r), bit0 = col-tile (0 or 128). W is [64][256] per side.
__global__ __launch_bounds__(256)
void lin2_kernel(const __hip_bfloat16* __restrict__ hin,
                 const void* __restrict__ Wl, const void* __restrict__ bl,
                 const void* __restrict__ Wr, const void* __restrict__ br,
                 __hip_bfloat16* __restrict__ xlp, __hip_bfloat16* __restrict__ xrp,
                 const int* __restrict__ flagp)
{
    const int isbf = *flagp;
    __shared__ float sh[64 * 64];
    __shared__ char  sWt[128 * 64 * 2];
    const int t = threadIdx.x;
    const int row0 = blockIdx.x * 64;
    const int side = blockIdx.y >> 1;
    const int col0 = (blockIdx.y & 1) * 128;
    const void* W  = side ? Wr : Wl;
    const void* bb = side ? br : bl;
    __hip_bfloat16* outp = side ? xrp : xlp;

    // stage input rows: 64x64 bf16 -> f32 (vectorized 16B loads)
#pragma unroll
    for (int i = 0; i < 2; ++i) {
        const int chunk = t + i * 256;
        const int r  = chunk >> 3;
        const int k0 = (chunk & 7) * 8;
        const int rr = row0 + r;
        int4 v = make_int4(0, 0, 0, 0);
        if (rr < N_NODES) v = *(const int4*)(hin + (long)rr * 64 + k0);
        float f[8];
        unpack8(v, f);
        float* dst = &sh[r * 64 + k0];
        *(float4*)dst       = make_float4(f[0], f[1], f[2], f[3]);
        *(float4*)(dst + 4) = make_float4(f[4], f[5], f[6], f[7]);
    }
    // stage weights transposed + swizzled, 16B per thread per iter:
    // chunk (c, kc): pack W[kc*8+j][col0+c] (j=0..7) -> one ds_write_b128.
    // slot index = kc ^ (c&7): each 16-lane phase group covers every slot 2x -> conflict-free.
#pragma unroll
    for (int i = 0; i < 4; ++i) {
        const int chunk = i * 256 + t;          // 1024 chunks
        const int c  = chunk & 127;
        const int kc = chunk >> 7;              // 0..7
        __hip_bfloat16 wb[8];
#pragma unroll
        for (int j = 0; j < 8; ++j)
            wb[j] = __float2bfloat16(ldf(W, (long)(kc * 8 + j) * 256 + col0 + c, isbf));
        const int byteoff = (c * 128 + kc * 16) ^ ((c & 7) << 4);
        *(int4*)(sWt + byteoff) = *(const int4*)wb;
    }
    __syncthreads();

    const int c = t & 127;
    const int rbase = (t >> 7) * 32;
    float acc[32];
    const float bv = ldf(bb, col0 + c, isbf);
#pragma unroll
    for (int j = 0; j < 32; ++j) acc[j] = bv;

    for (int k8 = 0; k8 < 8; ++k8) {
        const int byteoff = (c * 128 + k8 * 16) ^ ((c & 7) << 4);
        const int4 wv = *(const int4*)(sWt + byteoff);
        float w[8];
        unpack8(wv, w);
#pragma unroll
        for (int j = 0; j < 32; ++j) {
            const float4 s0 = *(const float4*)&sh[(rbase + j) * 64 + k8 * 8];
            const float4 s1 = *(const float4*)&sh[(rbase + j) * 64 + k8 * 8 + 4];
            acc[j] += s0.x * w[0] + s0.y * w[1] + s0.z * w[2] + s0.w * w[3]
                    + s1.x * w[4] + s1.y * w[5] + s1.z * w[6] + s1.w * w[7];
        }
    }
#pragma unroll
    for (int j = 0; j < 32; ++j) {
        const int rr = row0 + rbase + j;
        if (rr < N_NODES) outp[(long)rr * 256 + col0 + c] = __float2bfloat16(acc[j]);
    }
}

// ---------------- fused attention, layers 0/1: 16 lanes/edge, 4 edges/wave/iter ----------
__global__ __launch_bounds__(256)
void gat_fused16_kernel(const int* __restrict__ csr_src, const int* __restrict__ offsets,
                        const __hip_bfloat16* __restrict__ xl, const __hip_bfloat16* __restrict__ xr,
                        const void* __restrict__ att, const void* __restrict__ bias,
                        __hip_bfloat16* __restrict__ hout, const int* __restrict__ flagp)
{
    const int isbf = *flagp;
    const int node = blockIdx.x * 4 + (threadIdx.x >> 6);
    if (node >= N_NODES) return;
    const int lane = threadIdx.x & 63;
    const int l16 = lane & 15;            // lane covers channels l16*4 .. +4 (head = l16>>2)
    const int q = lane >> 4;              // quarter handles edges p ≡ q (mod 4)
    float a[4], xrv[4];
    {
        const int2 v = *(const int2*)(xr + (long)node * 64 + l16 * 4);
        unpack4(v, xrv);
#pragma unroll
        for (int j = 0; j < 4; ++j) a[j] = ldf(att, l16 * 4 + j, isbf);
    }
    const int beg = offsets[node], end = offsets[node + 1];
    float m = NEG_BIG, s = 0.f, acc[4] = {0.f, 0.f, 0.f, 0.f};
    for (int p = beg + q; p < end; p += 4) {
        const int src = csr_src[p];
        const int2 v = *(const int2*)(xl + (long)src * 64 + l16 * 4);
        float xlv[4]; unpack4(v, xlv);
        float t = 0.f;
#pragma unroll
        for (int j = 0; j < 4; ++j) {
            float u = xlv[j] + xrv[j];
            u = u > 0.f ? u : NEG_SLOPE * u;
            t += u * a[j];
        }
        t += __shfl_xor(t, 1); t += __shfl_xor(t, 2);   // 16-ch head dot (4 lanes)
        const float mn = fmaxf(m, t);
        const float sc = __expf(m - mn);
        const float w  = __expf(t - mn);
        s = s * sc + w;
#pragma unroll
        for (int j = 0; j < 4; ++j) acc[j] = acc[j] * sc + w * xlv[j];
        m = mn;
    }
    // merge 4 quarter-states (NaN-free via NEG_BIG sentinel)
#pragma unroll
    for (int step = 16; step <= 32; step <<= 1) {
        const float m_p = __shfl_xor(m, step);
        const float s_p = __shfl_xor(s, step);
        const float mm = fmaxf(m, m_p);
        const float e0 = __expf(m - mm), e1 = __expf(m_p - mm);
        s = s * e0 + s_p * e1;
#pragma unroll
        for (int j = 0; j < 4; ++j) {
            const float ap = __shfl_xor(acc[j], step);
            acc[j] = acc[j] * e0 + ap * e1;
        }
        m = mm;
    }
    if (q == 0) {
        __hip_bfloat16 ob[4];
#pragma unroll
        for (int j = 0; j < 4; ++j) {
            float o = acc[j] / (s + EPS_) + ldf(bias, l16 * 4 + j, isbf);
            o = o > 0.f ? o : (__expf(o) - 1.f);   // ELU
            ob[j] = __float2bfloat16(o);
        }
        *(int2*)(hout + (long)node * 64 + l16 * 4) = *(int2*)ob;
    }
}

// ---------------- layer 2: all 4 heads per edge, half-wave/edge, fused mean+bias ---------
__global__ __launch_bounds__(256)
void gat256_kernel(const int* __restrict__ csr_src, const int* __restrict__ offsets,
                   const __hip_bfloat16* __restrict__ xl2, const __hip_bfloat16* __restrict__ xr2,
                   const void* __restrict__ att, const void* __restrict__ bias,
                   void* __restrict__ out, const int* __restrict__ flagp)
{
    const int isbf = *flagp;
    const int node = blockIdx.x * 4 + (threadIdx.x >> 6);
    if (node >= N_NODES) return;
    const int lane = threadIdx.x & 63;
    const int l32 = lane & 31;            // covers global channels l32*8 .. +8 (head = l32>>3)
    const int half = lane >> 5;
    float a[8], xrv[8];
    {
        const int4 v = *(const int4*)(xr2 + (long)node * 256 + l32 * 8);
        unpack8(v, xrv);
#pragma unroll
        for (int j = 0; j < 8; ++j) a[j] = ldf(att, l32 * 8 + j, isbf);
    }
    const int beg = offsets[node], end = offsets[node + 1];
    float m = NEG_BIG, s = 0.f;
    float acc[8] = {0.f, 0.f, 0.f, 0.f, 0.f, 0.f, 0.f, 0.f};
    for (int p = beg + half; p < end; p += 2) {
        const int src = csr_src[p];
        const int4 v = *(const int4*)(xl2 + (long)src * 256 + l32 * 8);  // 512B/edge, one visit
        float xlv[8]; unpack8(v, xlv);
        float t = 0.f;
#pragma unroll
        for (int j = 0; j < 8; ++j) {
            float u = xlv[j] + xrv[j];
            u = u > 0.f ? u : NEG_SLOPE * u;
            t += u * a[j];
        }
        t += __shfl_xor(t, 1); t += __shfl_xor(t, 2); t += __shfl_xor(t, 4);  // 64-ch head dot
        const float mn = fmaxf(m, t);
        const float sc = __expf(m - mn);
        const float w  = __expf(t - mn);
        s = s * sc + w;
#pragma unroll
        for (int j = 0; j < 8; ++j) acc[j] = acc[j] * sc + w * xlv[j];
        m = mn;
    }
    // merge the two half-wave states
    {
        const float m_p = __shfl_xor(m, 32);
        const float s_p = __shfl_xor(s, 32);
        const float mm = fmaxf(m, m_p);
        const float e0 = __expf(m - mm), e1 = __expf(m_p - mm);
        s = s * e0 + s_p * e1;
#pragma unroll
        for (int j = 0; j < 8; ++j) {
            const float ap = __shfl_xor(acc[j], 32);
            acc[j] = acc[j] * e0 + ap * e1;
        }
    }
    const float inv = 1.f / (s + EPS_);
#pragma unroll
    for (int j = 0; j < 8; ++j) acc[j] *= inv;
    // head mean: butterfly over head bits (3,4) of l32; channel block (l32&7) preserved
#pragma unroll
    for (int j = 0; j < 8; ++j) {
        acc[j] += __shfl_xor(acc[j], 8);
        acc[j] += __shfl_xor(acc[j], 16);
        acc[j] *= 0.25f;
    }
    if (lane < 8) {
        const int c0 = lane * 8;
        if (isbf) {
            __hip_bfloat16 ob[8];
#pragma unroll
            for (int j = 0; j < 8; ++j)
                ob[j] = __float2bfloat16(acc[j] + ldf(bias, c0 + j, isbf));
            *(int4*)((__hip_bfloat16*)out + (long)node * 64 + c0) = *(const int4*)ob;
        } else {
            float* po = (float*)out + (long)node * 64 + c0;
#pragma unroll
            for (int j = 0; j < 8; ++j) po[j] = acc[j] + ldf(bias, c0 + j, isbf);
        }
    }
}

static inline int cdiv(int a, int b) { return (a + b - 1) / b; }

extern "C" void kernel_launch(void* const* d_in, const int* in_sizes, int n_in,
                              void* d_out, int out_size, void* d_ws, size_t ws_size,
                              hipStream_t stream)
{
    const void* x   = d_in[0];
    const int*  ei  = (const int*)d_in[1];
    const void* Wl0 = d_in[2];  const void* bl0 = d_in[3];
    const void* Wr0 = d_in[4];  const void* br0 = d_in[5];
    const void* att0  = d_in[6];  const void* bias0 = d_in[7];
    const void* Wl1 = d_in[8];  const void* bl1 = d_in[9];
    const void* Wr1 = d_in[10]; const void* br1 = d_in[11];
    const void* att1  = d_in[12]; const void* bias1 = d_in[13];
    const void* Wl2 = d_in[14]; const void* bl2 = d_in[15];
    const void* Wr2 = d_in[16]; const void* br2 = d_in[17];
    const void* att2  = d_in[18]; const void* bias2 = d_in[19];

    // workspace layout (~59.8 MB), f32-slot offsets
    float* ws = (float*)d_ws;
    __hip_bfloat16* hbuf = (__hip_bfloat16*)ws;                  // [N,64] bf16
    __hip_bfloat16* xl2  = (__hip_bfloat16*)(ws + 1600000);      // [N,256] bf16
    __hip_bfloat16* xr2  = (__hip_bfloat16*)(ws + 8000000);      // [N,256] bf16
    __hip_bfloat16* xl   = xl2;                                  // [N,64] alias (layers 0/1)
    __hip_bfloat16* xr   = (__hip_bfloat16*)(ws + 4800000);      // [N,64] alias
    int* csr    = (int*)(ws + 14400000);                         // 450k
    int* offs   = csr + 450000;                                  // 50001
    int* counts = offs + 50004;                                  // 50k (doubles as fill cursor)
    int* bsum   = counts + 50000;
    int* bpre   = bsum + 256;
    int* flag   = bpre + 256;

    const int NGE = cdiv(N_ETOT, 256);
    const int NGW = cdiv(N_NODES, 4);
    const int NGL = cdiv(N_NODES, 32);

    // ---- CSR build (no memsets: zeroing/cursor folded into kernels) ----
    detect_zero_kernel<<<SCAN_BLOCKS, 256, 0, stream>>>(x, flag, counts);
    count_kernel<<<NGE, 256, 0, stream>>>(ei, counts);
    scan_phase1<<<SCAN_BLOCKS, 256, 0, stream>>>(counts, bsum);
    scan_phase2<<<1, 256, 0, stream>>>(bsum, bpre, offs);
    scan_phase3<<<SCAN_BLOCKS, 256, 0, stream>>>(counts, bpre, offs);
    fill_kernel<<<NGE, 256, 0, stream>>>(ei, counts, csr);

    // ---- layer 0 ----
    lin_dual_kernel<true><<<NGL, 256, 0, stream>>>(x, Wl0, bl0, Wr0, br0, xl, xr, flag);
    gat_fused16_kernel<<<NGW, 256, 0, stream>>>(csr, offs, xl, xr, att0, bias0, hbuf, flag);

    // ---- layer 1 ----
    lin_dual_kernel<false><<<NGL, 256, 0, stream>>>(hbuf, Wl1, bl1, Wr1, br1, xl, xr, flag);
    gat_fused16_kernel<<<NGW, 256, 0, stream>>>(csr, offs, xl, xr, att1, bias1, hbuf, flag);

    // ---- layer 2: fast linear, then one all-heads pass ----
    {
        dim3 g2(cdiv(N_NODES, 64), 4);
        lin2_kernel<<<g2, 256, 0, stream>>>(hbuf, Wl2, bl2, Wr2, br2, xl2, xr2, flag);
    }
    gat256_kernel<<<NGW, 256, 0, stream>>>(csr, offs, xl2, xr2, att2, bias2, d_out, flag);
}

// Round 10
// 286.650 us; speedup vs baseline: 38.6213x; 1.2910x over previous
//
#include <hip/hip_runtime.h>
#include <hip/hip_bf16.h>

#define N_NODES 50000
#define N_EDGES 400000
#define N_ETOT  (N_EDGES + N_NODES)
#define NHEADS  4
#define SCAN_BLOCKS 196   // cdiv(N_NODES, 256)

static constexpr float NEG_SLOPE = 0.2f;
static constexpr float EPS_ = 1e-16f;
static constexpr float NEG_BIG = -1e30f;   // NaN-free empty-segment sentinel

typedef __attribute__((ext_vector_type(8))) short bf16x8;
typedef __attribute__((ext_vector_type(4))) float f32x4;

__device__ __forceinline__ float b2f(__hip_bfloat16 v) { return __bfloat162float(v); }
__device__ __forceinline__ float ldf(const void* p, long i, int isbf) {
    return isbf ? b2f(((const __hip_bfloat16*)p)[i]) : ((const float*)p)[i];
}
__device__ __forceinline__ void unpack8(int4 v, float* f) {
    const unsigned* u = (const unsigned*)&v;
#pragma unroll
    for (int i = 0; i < 4; ++i) {
        f[2 * i]     = __uint_as_float(u[i] << 16);
        f[2 * i + 1] = __uint_as_float(u[i] & 0xffff0000u);
    }
}
__device__ __forceinline__ void unpack4(int2 v, float* f) {
    const unsigned* u = (const unsigned*)&v;
    f[0] = __uint_as_float(u[0] << 16);
    f[1] = __uint_as_float(u[0] & 0xffff0000u);
    f[2] = __uint_as_float(u[1] << 16);
    f[3] = __uint_as_float(u[1] & 0xffff0000u);
}

// ---------------- dtype detector + counts zeroing (fused) ----------------
__global__ __launch_bounds__(256)
void detect_zero_kernel(const void* __restrict__ x, int* __restrict__ flag,
                        int* __restrict__ counts)
{
    const int idx = blockIdx.x * 256 + threadIdx.x;
    if (idx < N_NODES) counts[idx] = 0;
    if (blockIdx.x != 0) return;
    __shared__ int cnt;
    if (threadIdx.x == 0) cnt = 0;
    __syncthreads();
    int local = 0;
    const __hip_bfloat16* p = (const __hip_bfloat16*)x;
    for (int i = threadIdx.x; i < 4096; i += 256) {
        float v = b2f(p[2 * i]);
        if (!(fabsf(v) < 64.f)) local++;
    }
    atomicAdd(&cnt, local);
    __syncthreads();
    if (threadIdx.x == 0) *flag = (cnt < 64) ? 1 : 0;
}

// ---------------- weight prep: transpose all 6 W to [c][64] bf16 panels ----------------
// panel offsets (bf16 elems): L0:0 R0:4096 L1:8192 R1:12288 L2:16384 R2:32768 (end 49152)
__global__ __launch_bounds__(256)
void prep_w_kernel(const void* __restrict__ Wl0, const void* __restrict__ Wr0,
                   const void* __restrict__ Wl1, const void* __restrict__ Wr1,
                   const void* __restrict__ Wl2, const void* __restrict__ Wr2,
                   __hip_bfloat16* __restrict__ wt, const int* __restrict__ flagp)
{
    const int isbf = *flagp;
    int idx = blockIdx.x * 256 + threadIdx.x;   // 0..49151
    const void* W; int dout, obase;
    if      (idx <  4096) { W = Wl0; dout = 64;  obase = 0; }
    else if (idx <  8192) { W = Wr0; dout = 64;  obase = 4096;  idx -= 4096; }
    else if (idx < 12288) { W = Wl1; dout = 64;  obase = 8192;  idx -= 8192; }
    else if (idx < 16384) { W = Wr1; dout = 64;  obase = 12288; idx -= 12288; }
    else if (idx < 32768) { W = Wl2; dout = 256; obase = 16384; idx -= 16384; }
    else                  { W = Wr2; dout = 256; obase = 32768; idx -= 32768; }
    const int k = idx / dout, c = idx % dout;
    wt[obase + c * 64 + k] = __float2bfloat16(ldf(W, idx, isbf));
}

// ---------------- CSR build ----------------
__global__ __launch_bounds__(256)
void count_kernel(const int* __restrict__ ei, int* __restrict__ counts)
{
    const int e = blockIdx.x * 256 + threadIdx.x;
    if (e >= N_ETOT) return;
    const int d = (e < N_EDGES) ? ei[N_EDGES + e] : e - N_EDGES;
    atomicAdd(&counts[d], 1);
}

__global__ __launch_bounds__(256)
void scan_phase1(const int* __restrict__ counts, int* __restrict__ bsum)
{
    __shared__ int sh[256];
    const int idx = blockIdx.x * 256 + threadIdx.x;
    sh[threadIdx.x] = (idx < N_NODES) ? counts[idx] : 0;
    __syncthreads();
    for (int off = 128; off > 0; off >>= 1) {
        if (threadIdx.x < off) sh[threadIdx.x] += sh[threadIdx.x + off];
        __syncthreads();
    }
    if (threadIdx.x == 0) bsum[blockIdx.x] = sh[0];
}

__global__ __launch_bounds__(256)
void scan_phase2(const int* __restrict__ bsum, int* __restrict__ bpre, int* __restrict__ offs)
{
    __shared__ int sh[256];
    const int t = threadIdx.x;
    const int v = (t < SCAN_BLOCKS) ? bsum[t] : 0;
    sh[t] = v;
    __syncthreads();
    for (int off = 1; off < 256; off <<= 1) {
        int u = (t >= off) ? sh[t - off] : 0;
        __syncthreads();
        sh[t] += u;
        __syncthreads();
    }
    if (t < SCAN_BLOCKS) bpre[t] = sh[t] - v;
    if (t == 0) offs[N_NODES] = N_ETOT;
}

__global__ __launch_bounds__(256)
void scan_phase3(int* __restrict__ counts, const int* __restrict__ bpre,
                 int* __restrict__ offs)
{
    __shared__ int sh[256];
    const int t = threadIdx.x;
    const int idx = blockIdx.x * 256 + t;
    const int v = (idx < N_NODES) ? counts[idx] : 0;
    sh[t] = v;
    __syncthreads();
    for (int off = 1; off < 256; off <<= 1) {
        int u = (t >= off) ? sh[t - off] : 0;
        __syncthreads();
        sh[t] += u;
        __syncthreads();
    }
    if (idx < N_NODES) {
        const int o = bpre[blockIdx.x] + sh[t] - v;
        offs[idx] = o;
        counts[idx] = o;      // counts becomes the fill cursor
    }
}

__global__ __launch_bounds__(256)
void fill_kernel(const int* __restrict__ ei, int* __restrict__ cursor,
                 int* __restrict__ csr_src)
{
    const int e = blockIdx.x * 256 + threadIdx.x;
    if (e >= N_ETOT) return;
    int s, d;
    if (e < N_EDGES) { s = ei[e]; d = ei[N_EDGES + e]; } else { s = d = e - N_EDGES; }
    const int pos = atomicAdd(&cursor[d], 1);
    csr_src[pos] = s;
}

// ---------------- MFMA linear: out[N,LD] = hin[N,64] @ W + b, both sides ----------------
// blockIdx.y: bit0 = side, rest = 64-col chunk. Wave: 16 rows x 64 cols, K=64 (2 MFMA/tile).
// A frag: lane holds hin[r0+(l&15)][ (l>>4)*8 .. +8 ]; B frag from pre-transposed wt[c][64].
// C/D: col=lane&15, row=(lane>>4)*4+reg  [m89-verified].
template<int NCHUNK, bool EXT>
__global__ __launch_bounds__(256)
void lin_mfma_kernel(const void* __restrict__ hin, const __hip_bfloat16* __restrict__ wt,
                     int offL, int offR,
                     const void* __restrict__ bL, const void* __restrict__ bR,
                     __hip_bfloat16* __restrict__ outL, __hip_bfloat16* __restrict__ outR,
                     const int* __restrict__ flagp)
{
    constexpr int LD = NCHUNK * 64;
    const int isbf = *flagp;
    const int side  = blockIdx.y & 1;
    const int chunk = blockIdx.y >> 1;
    const __hip_bfloat16* wpanel = wt + (side ? offR : offL);
    const void* bb = side ? bR : bL;
    __hip_bfloat16* outp = side ? outR : outL;

    const int lane = threadIdx.x & 63;
    const int w = threadIdx.x >> 6;
    const int r0 = blockIdx.x * 64 + w * 16;
    const int arow = r0 + (lane & 15);
    const int kb = (lane >> 4) * 8;

    bf16x8 a0 = {}, a1 = {};
    if (arow < N_NODES) {
        if (EXT && !isbf) {
            const float* pf = (const float*)hin + (long)arow * 64;
            short t0[8], t1[8];
#pragma unroll
            for (int j = 0; j < 8; ++j) {
                __hip_bfloat16 h0 = __float2bfloat16(pf[kb + j]);
                __hip_bfloat16 h1 = __float2bfloat16(pf[32 + kb + j]);
                t0[j] = *(short*)&h0; t1[j] = *(short*)&h1;
            }
            a0 = *(const bf16x8*)t0; a1 = *(const bf16x8*)t1;
        } else {
            const __hip_bfloat16* pb = (const __hip_bfloat16*)hin + (long)arow * 64;
            a0 = *(const bf16x8*)(pb + kb);
            a1 = *(const bf16x8*)(pb + 32 + kb);
        }
    }

    f32x4 acc[4];
#pragma unroll
    for (int ct = 0; ct < 4; ++ct) {
        const __hip_bfloat16* wc = wpanel + (long)(chunk * 64 + ct * 16 + (lane & 15)) * 64 + kb;
        const bf16x8 b0 = *(const bf16x8*)wc;
        const bf16x8 b1 = *(const bf16x8*)(wc + 32);
        f32x4 z = {0.f, 0.f, 0.f, 0.f};
        z = __builtin_amdgcn_mfma_f32_16x16x32_bf16(a0, b0, z, 0, 0, 0);
        acc[ct] = __builtin_amdgcn_mfma_f32_16x16x32_bf16(a1, b1, z, 0, 0, 0);
    }

    const int crow0 = r0 + (lane >> 4) * 4;
#pragma unroll
    for (int ct = 0; ct < 4; ++ct) {
        const int col = chunk * 64 + ct * 16 + (lane & 15);
        const float bv = ldf(bb, col, isbf);
#pragma unroll
        for (int reg = 0; reg < 4; ++reg) {
            const int row = crow0 + reg;
            if (row < N_NODES)
                outp[(long)row * LD + col] = __float2bfloat16(acc[ct][reg] + bv);
        }
    }
}

// ---------------- fused attention, layers 0/1: 16 lanes/edge, 4 edges/wave/iter ----------
__global__ __launch_bounds__(256)
void gat_fused16_kernel(const int* __restrict__ csr_src, const int* __restrict__ offsets,
                        const __hip_bfloat16* __restrict__ xl, const __hip_bfloat16* __restrict__ xr,
                        const void* __restrict__ att, const void* __restrict__ bias,
                        __hip_bfloat16* __restrict__ hout, const int* __restrict__ flagp)
{
    const int isbf = *flagp;
    const int node = blockIdx.x * 4 + (threadIdx.x >> 6);
    if (node >= N_NODES) return;
    const int lane = threadIdx.x & 63;
    const int l16 = lane & 15;            // lane covers channels l16*4 .. +4 (head = l16>>2)
    const int q = lane >> 4;              // quarter handles edges p ≡ q (mod 4)
    float a[4], xrv[4];
    {
        const int2 v = *(const int2*)(xr + (long)node * 64 + l16 * 4);
        unpack4(v, xrv);
#pragma unroll
        for (int j = 0; j < 4; ++j) a[j] = ldf(att, l16 * 4 + j, isbf);
    }
    const int beg = offsets[node], end = offsets[node + 1];
    float m = NEG_BIG, s = 0.f, acc[4] = {0.f, 0.f, 0.f, 0.f};
    for (int p = beg + q; p < end; p += 4) {
        const int src = csr_src[p];
        const int2 v = *(const int2*)(xl + (long)src * 64 + l16 * 4);
        float xlv[4]; unpack4(v, xlv);
        float t = 0.f;
#pragma unroll
        for (int j = 0; j < 4; ++j) {
            float u = xlv[j] + xrv[j];
            u = u > 0.f ? u : NEG_SLOPE * u;
            t += u * a[j];
        }
        t += __shfl_xor(t, 1); t += __shfl_xor(t, 2);   // 16-ch head dot (4 lanes)
        const float mn = fmaxf(m, t);
        const float sc = __expf(m - mn);
        const float w  = __expf(t - mn);
        s = s * sc + w;
#pragma unroll
        for (int j = 0; j < 4; ++j) acc[j] = acc[j] * sc + w * xlv[j];
        m = mn;
    }
    // merge 4 quarter-states (NaN-free via NEG_BIG sentinel)
#pragma unroll
    for (int step = 16; step <= 32; step <<= 1) {
        const float m_p = __shfl_xor(m, step);
        const float s_p = __shfl_xor(s, step);
        const float mm = fmaxf(m, m_p);
        const float e0 = __expf(m - mm), e1 = __expf(m_p - mm);
        s = s * e0 + s_p * e1;
#pragma unroll
        for (int j = 0; j < 4; ++j) {
            const float ap = __shfl_xor(acc[j], step);
            acc[j] = acc[j] * e0 + ap * e1;
        }
        m = mm;
    }
    if (q == 0) {
        __hip_bfloat16 ob[4];
#pragma unroll
        for (int j = 0; j < 4; ++j) {
            float o = acc[j] / (s + EPS_) + ldf(bias, l16 * 4 + j, isbf);
            o = o > 0.f ? o : (__expf(o) - 1.f);   // ELU
            ob[j] = __float2bfloat16(o);
        }
        *(int2*)(hout + (long)node * 64 + l16 * 4) = *(int2*)ob;
    }
}

// ---------------- layer 2: all 4 heads per edge, half-wave/edge, fused mean+bias ---------
__global__ __launch_bounds__(256)
void gat256_kernel(const int* __restrict__ csr_src, const int* __restrict__ offsets,
                   const __hip_bfloat16* __restrict__ xl2, const __hip_bfloat16* __restrict__ xr2,
                   const void* __restrict__ att, const void* __restrict__ bias,
                   void* __restrict__ out, const int* __restrict__ flagp)
{
    const int isbf = *flagp;
    const int node = blockIdx.x * 4 + (threadIdx.x >> 6);
    if (node >= N_NODES) return;
    const int lane = threadIdx.x & 63;
    const int l32 = lane & 31;            // covers global channels l32*8 .. +8 (head = l32>>3)
    const int half = lane >> 5;
    float a[8], xrv[8];
    {
        const int4 v = *(const int4*)(xr2 + (long)node * 256 + l32 * 8);
        unpack8(v, xrv);
#pragma unroll
        for (int j = 0; j < 8; ++j) a[j] = ldf(att, l32 * 8 + j, isbf);
    }
    const int beg = offsets[node], end = offsets[node + 1];
    float m = NEG_BIG, s = 0.f;
    float acc[8] = {0.f, 0.f, 0.f, 0.f, 0.f, 0.f, 0.f, 0.f};
    for (int p = beg + half; p < end; p += 2) {
        const int src = csr_src[p];
        const int4 v = *(const int4*)(xl2 + (long)src * 256 + l32 * 8);  // 512B/edge, one visit
        float xlv[8]; unpack8(v, xlv);
        float t = 0.f;
#pragma unroll
        for (int j = 0; j < 8; ++j) {
            float u = xlv[j] + xrv[j];
            u = u > 0.f ? u : NEG_SLOPE * u;
            t += u * a[j];
        }
        t += __shfl_xor(t, 1); t += __shfl_xor(t, 2); t += __shfl_xor(t, 4);  // 64-ch head dot
        const float mn = fmaxf(m, t);
        const float sc = __expf(m - mn);
        const float w  = __expf(t - mn);
        s = s * sc + w;
#pragma unroll
        for (int j = 0; j < 8; ++j) acc[j] = acc[j] * sc + w * xlv[j];
        m = mn;
    }
    // merge the two half-wave states
    {
        const float m_p = __shfl_xor(m, 32);
        const float s_p = __shfl_xor(s, 32);
        const float mm = fmaxf(m, m_p);
        const float e0 = __expf(m - mm), e1 = __expf(m_p - mm);
        s = s * e0 + s_p * e1;
#pragma unroll
        for (int j = 0; j < 8; ++j) {
            const float ap = __shfl_xor(acc[j], 32);
            acc[j] = acc[j] * e0 + ap * e1;
        }
    }
    const float inv = 1.f / (s + EPS_);
#pragma unroll
    for (int j = 0; j < 8; ++j) acc[j] *= inv;
    // head mean: butterfly over head bits (3,4) of l32; channel block (l32&7) preserved
#pragma unroll
    for (int j = 0; j < 8; ++j) {
        acc[j] += __shfl_xor(acc[j], 8);
        acc[j] += __shfl_xor(acc[j], 16);
        acc[j] *= 0.25f;
    }
    if (lane < 8) {
        const int c0 = lane * 8;
        if (isbf) {
            __hip_bfloat16 ob[8];
#pragma unroll
            for (int j = 0; j < 8; ++j)
                ob[j] = __float2bfloat16(acc[j] + ldf(bias, c0 + j, isbf));
            *(int4*)((__hip_bfloat16*)out + (long)node * 64 + c0) = *(const int4*)ob;
        } else {
            float* po = (float*)out + (long)node * 64 + c0;
#pragma unroll
            for (int j = 0; j < 8; ++j) po[j] = acc[j] + ldf(bias, c0 + j, isbf);
        }
    }
}

static inline int cdiv(int a, int b) { return (a + b - 1) / b; }

extern "C" void kernel_launch(void* const* d_in, const int* in_sizes, int n_in,
                              void* d_out, int out_size, void* d_ws, size_t ws_size,
                              hipStream_t stream)
{
    const void* x   = d_in[0];
    const int*  ei  = (const int*)d_in[1];
    const void* Wl0 = d_in[2];  const void* bl0 = d_in[3];
    const void* Wr0 = d_in[4];  const void* br0 = d_in[5];
    const void* att0  = d_in[6];  const void* bias0 = d_in[7];
    const void* Wl1 = d_in[8];  const void* bl1 = d_in[9];
    const void* Wr1 = d_in[10]; const void* br1 = d_in[11];
    const void* att1  = d_in[12]; const void* bias1 = d_in[13];
    const void* Wl2 = d_in[14]; const void* bl2 = d_in[15];
    const void* Wr2 = d_in[16]; const void* br2 = d_in[17];
    const void* att2  = d_in[18]; const void* bias2 = d_in[19];

    // workspace layout (~59.9 MB), f32-slot offsets
    float* ws = (float*)d_ws;
    __hip_bfloat16* hbuf = (__hip_bfloat16*)ws;                  // [N,64] bf16
    __hip_bfloat16* xl2  = (__hip_bfloat16*)(ws + 1600000);      // [N,256] bf16
    __hip_bfloat16* xr2  = (__hip_bfloat16*)(ws + 8000000);      // [N,256] bf16
    __hip_bfloat16* xl   = xl2;                                  // [N,64] alias (layers 0/1)
    __hip_bfloat16* xr   = (__hip_bfloat16*)(ws + 4800000);      // [N,64] alias
    int* csr    = (int*)(ws + 14400000);                         // 450k
    int* offs   = csr + 450000;                                  // 50001
    int* counts = offs + 50004;                                  // 50k (doubles as fill cursor)
    int* bsum   = counts + 50000;
    int* bpre   = bsum + 256;
    int* flag   = bpre + 256;
    __hip_bfloat16* wt = (__hip_bfloat16*)(flag + 4);            // 49152 bf16 panels (96 KB)

    const int NGE = cdiv(N_ETOT, 256);
    const int NGW = cdiv(N_NODES, 4);
    const int NGM = cdiv(N_NODES, 64);

    // ---- prep: dtype flag + counts zero, weight transpose ----
    detect_zero_kernel<<<SCAN_BLOCKS, 256, 0, stream>>>(x, flag, counts);
    prep_w_kernel<<<192, 256, 0, stream>>>(Wl0, Wr0, Wl1, Wr1, Wl2, Wr2, wt, flag);

    // ---- CSR build ----
    count_kernel<<<NGE, 256, 0, stream>>>(ei, counts);
    scan_phase1<<<SCAN_BLOCKS, 256, 0, stream>>>(counts, bsum);
    scan_phase2<<<1, 256, 0, stream>>>(bsum, bpre, offs);
    scan_phase3<<<SCAN_BLOCKS, 256, 0, stream>>>(counts, bpre, offs);
    fill_kernel<<<NGE, 256, 0, stream>>>(ei, counts, csr);

    // ---- layer 0 ----
    lin_mfma_kernel<1, true><<<dim3(NGM, 2), 256, 0, stream>>>(
        x, wt, 0, 4096, bl0, br0, xl, xr, flag);
    gat_fused16_kernel<<<NGW, 256, 0, stream>>>(csr, offs, xl, xr, att0, bias0, hbuf, flag);

    // ---- layer 1 ----
    lin_mfma_kernel<1, false><<<dim3(NGM, 2), 256, 0, stream>>>(
        hbuf, wt, 8192, 12288, bl1, br1, xl, xr, flag);
    gat_fused16_kernel<<<NGW, 256, 0, stream>>>(csr, offs, xl, xr, att1, bias1, hbuf, flag);

    // ---- layer 2: MFMA linear (2 sides x 4 col-chunks), then one all-heads pass ----
    lin_mfma_kernel<4, false><<<dim3(NGM, 8), 256, 0, stream>>>(
        hbuf, wt, 16384, 32768, bl2, br2, xl2, xr2, flag);
    gat256_kernel<<<NGW, 256, 0, stream>>>(csr, offs, xl2, xr2, att2, bias2, d_out, flag);
}